// Round 19
// baseline (363.189 us; speedup 1.0000x reference)
//
#include <hip/hip_runtime.h>

typedef short bf16x8 __attribute__((ext_vector_type(8)));
typedef float f32x4 __attribute__((ext_vector_type(4)));
typedef float f32x2 __attribute__((ext_vector_type(2)));
typedef unsigned short u16;
typedef u16 u16x4 __attribute__((ext_vector_type(4)));

#define L_SEQ 1024
#define IDIM_ 2048
#define H_ 16
#define DK_ 128
#define DV_ 128
#define KEYD 2048
#define VALD 2048
#define CONVD 6144
#define QZD 8320          // qkv(6144) | z(2048) | b(16) | a(16) | pad(96)
#define GCOL 8192
#define SCH 64
#define NSC (L_SEQ / SCH)

__device__ __forceinline__ u16 f2bf(float f) {
  union { float f; unsigned u; } v; v.f = f;
  unsigned r = v.u + 0x7FFF + ((v.u >> 16) & 1);  // RNE
  return (u16)(r >> 16);
}

// 16-lane allreduce, all-DPP. Verified R3-R18.
__device__ __forceinline__ float red16(float x) {
  union U { float f; int i; } a, t;
  a.f = x;
  t.i = __builtin_amdgcn_update_dpp(0, a.i, 0xB1, 0xF, 0xF, true); a.f += t.f;
  t.i = __builtin_amdgcn_update_dpp(0, a.i, 0x4E, 0xF, 0xF, true); a.f += t.f;
  t.i = __builtin_amdgcn_update_dpp(0, a.i, 0x141, 0xF, 0xF, true); a.f += t.f;
  t.i = __builtin_amdgcn_update_dpp(0, a.i, 0x140, 0xF, 0xF, true); a.f += t.f;
  return a.f;
}

// ---- merged cast/transpose prep (R18-exact) ----
__global__ __launch_bounds__(256) void prepcast_kernel(const float* __restrict__ x,
                                                       const float* __restrict__ Wqkv,
                                                       const float* __restrict__ Wz,
                                                       const float* __restrict__ Wb,
                                                       const float* __restrict__ Wa,
                                                       const float* __restrict__ Wout,
                                                       u16* __restrict__ xb,
                                                       u16* __restrict__ WcatT,
                                                       u16* __restrict__ WoutT) {
  __shared__ float tile[32][33];
  const int bid = blockIdx.x;
  if (bid < 2048) {
    int i = (bid * 256 + threadIdx.x) * 4;
    f32x4 v = *(const f32x4*)&x[i];
    u16x4 o = { f2bf(v[0]), f2bf(v[1]), f2bf(v[2]), f2bf(v[3]) };
    *(u16x4*)&xb[i] = o;
    return;
  }
  if (bid >= 22592) {
    size_t off = (size_t)8224 * IDIM_ + (size_t)(bid - 22592) * 8192 + threadIdx.x * 32;
    u16x4 z = {0, 0, 0, 0};
#pragma unroll
    for (int j = 0; j < 8; ++j) *(u16x4*)&WcatT[off + j * 4] = z;
    return;
  }
  if (bid >= 22528) {
    int by = bid - 22528;
    int r = threadIdx.x >> 3, c8 = threadIdx.x & 7;
    int row = by * 32 + r;
#pragma unroll
    for (int cc = 0; cc < 2; ++cc) {
      int c = cc * 8 + c8;
      WcatT[(size_t)(GCOL + c) * IDIM_ + row]      = f2bf(Wb[(size_t)row * 16 + c]);
      WcatT[(size_t)(GCOL + 16 + c) * IDIM_ + row] = f2bf(Wa[(size_t)row * 16 + c]);
    }
    return;
  }
  const float* W; u16* WT; int R, C, bx, by;
  if (bid < 14336) {
    int t = bid - 2048;  bx = t % 192; by = t / 192;
    W = Wqkv; WT = WcatT; R = IDIM_; C = CONVD;
  } else if (bid < 18432) {
    int t = bid - 14336; bx = t & 63; by = t >> 6;
    W = Wz; WT = WcatT + (size_t)CONVD * IDIM_; R = IDIM_; C = VALD;
  } else {
    int t = bid - 18432; bx = t & 63; by = t >> 6;
    W = Wout; WT = WoutT; R = VALD; C = IDIM_;
  }
  int c0 = bx * 32, r0 = by * 32;
  int tx = threadIdx.x & 31, ty = threadIdx.x >> 5;
#pragma unroll
  for (int j = 0; j < 4; ++j)
    tile[ty + j * 8][tx] = W[(size_t)(r0 + ty + j * 8) * C + c0 + tx];
  __syncthreads();
#pragma unroll
  for (int j = 0; j < 4; ++j)
    WT[(size_t)(c0 + ty + j * 8) * R + r0 + tx] = f2bf(tile[tx][ty + j * 8]);
}

// ---------------- NT GEMM (R18-exact) ----------------
__global__ __launch_bounds__(256) void gemm_bt_kernel(const u16* __restrict__ A,
                                                      const u16* __restrict__ B,
                                                      float* __restrict__ C,
                                                      int M, int N, int K) {
  __shared__ short As[128 * 72];
  __shared__ short Bs[128 * 72];
  const int tid = threadIdx.x;
  const int lane = tid & 63, wave = tid >> 6;
  const int wm = wave >> 1, wn = wave & 1;
  const int m0 = blockIdx.y * 128, n0 = blockIdx.x * 128;
  const int l15 = lane & 15, lhi = lane >> 4;

  f32x4 acc[4][4] = {};

  for (int k0 = 0; k0 < K; k0 += 64) {
    __syncthreads();
#pragma unroll
    for (int i = 0; i < 4; ++i) {
      int chunk = tid + i * 256;
      int row = chunk >> 3;
      int kc = (chunk & 7) * 8;
      *(bf16x8*)&As[row * 72 + kc] =
          *(const bf16x8*)&A[(size_t)(m0 + row) * K + k0 + kc];
      *(bf16x8*)&Bs[row * 72 + kc] =
          *(const bf16x8*)&B[(size_t)(n0 + row) * K + k0 + kc];
    }
    __syncthreads();
#pragma unroll
    for (int kk = 0; kk < 64; kk += 32) {
      const int koff = kk + lhi * 8;
      bf16x8 a[4], b[4];
#pragma unroll
      for (int m = 0; m < 4; ++m)
        a[m] = *(const bf16x8*)&As[(wm * 64 + m * 16 + l15) * 72 + koff];
#pragma unroll
      for (int n = 0; n < 4; ++n)
        b[n] = *(const bf16x8*)&Bs[(wn * 64 + n * 16 + l15) * 72 + koff];
#pragma unroll
      for (int m = 0; m < 4; ++m)
#pragma unroll
        for (int n = 0; n < 4; ++n)
          acc[m][n] = __builtin_amdgcn_mfma_f32_16x16x32_bf16(a[m], b[n], acc[m][n], 0, 0, 0);
    }
  }
#pragma unroll
  for (int m = 0; m < 4; ++m)
#pragma unroll
    for (int n = 0; n < 4; ++n)
#pragma unroll
      for (int j = 0; j < 4; ++j) {
        int row = m0 + wm * 64 + m * 16 + lhi * 4 + j;
        int col = n0 + wn * 64 + n * 16 + l15;
        C[(size_t)row * N + col] = acc[m][n][j];
      }
}

// ---------------- NT GEMM BM=64 (R18-exact) ----------------
__global__ __launch_bounds__(256) void gemm_bt64_kernel(const u16* __restrict__ A,
                                                        const u16* __restrict__ B,
                                                        float* __restrict__ C,
                                                        int M, int N, int K, int cxl) {
  __shared__ short As[64 * 72];
  __shared__ short Bs[128 * 72];
  const int tid = threadIdx.x;
  const int lane = tid & 63, wave = tid >> 6;
  const int wm = wave >> 1, wn = wave & 1;
  const int bid = blockIdx.x;
  const int xcd = bid & 7, bi = bid >> 3;
  const int bx = (xcd << cxl) + (bi & ((1 << cxl) - 1));
  const int by = bi >> cxl;
  const int m0 = by * 64, n0 = bx * 128;
  const int l15 = lane & 15, lhi = lane >> 4;

  f32x4 acc[2][4] = {};

  for (int k0 = 0; k0 < K; k0 += 64) {
    __syncthreads();
#pragma unroll
    for (int i = 0; i < 2; ++i) {
      int chunk = tid + i * 256;
      int row = chunk >> 3;
      int kc = (chunk & 7) * 8;
      *(bf16x8*)&As[row * 72 + kc] =
          *(const bf16x8*)&A[(size_t)(m0 + row) * K + k0 + kc];
    }
#pragma unroll
    for (int i = 0; i < 4; ++i) {
      int chunk = tid + i * 256;
      int row = chunk >> 3;
      int kc = (chunk & 7) * 8;
      *(bf16x8*)&Bs[row * 72 + kc] =
          *(const bf16x8*)&B[(size_t)(n0 + row) * K + k0 + kc];
    }
    __syncthreads();
#pragma unroll
    for (int kk = 0; kk < 64; kk += 32) {
      const int koff = kk + lhi * 8;
      bf16x8 a[2], b[4];
#pragma unroll
      for (int m = 0; m < 2; ++m)
        a[m] = *(const bf16x8*)&As[(wm * 32 + m * 16 + l15) * 72 + koff];
#pragma unroll
      for (int n = 0; n < 4; ++n)
        b[n] = *(const bf16x8*)&Bs[(wn * 64 + n * 16 + l15) * 72 + koff];
#pragma unroll
      for (int m = 0; m < 2; ++m)
#pragma unroll
        for (int n = 0; n < 4; ++n)
          acc[m][n] = __builtin_amdgcn_mfma_f32_16x16x32_bf16(a[m], b[n], acc[m][n], 0, 0, 0);
    }
  }
#pragma unroll
  for (int m = 0; m < 2; ++m)
#pragma unroll
    for (int n = 0; n < 4; ++n)
#pragma unroll
      for (int j = 0; j < 4; ++j) {
        int row = m0 + wm * 32 + m * 16 + lhi * 4 + j;
        int col = n0 + wn * 64 + n * 16 + l15;
        C[(size_t)row * N + col] = acc[m][n][j];
      }
}

// -------- gatelite: gates from qkvz cols 8192..8223 (egT dropped) --------
__global__ __launch_bounds__(256) void gatelite_kernel(const float* __restrict__ qkvz,
                                                       const float* __restrict__ A_log,
                                                       const float* __restrict__ dt_bias,
                                                       float* __restrict__ btT,
                                                       float* __restrict__ gT) {
  int gid = blockIdx.x * 256 + threadIdx.x;  // 16384: l*16+h
  int l = gid >> 4, h = gid & 15;
  const float* row = qkvz + (size_t)l * QZD + GCOL;
  float b = row[h], a = row[16 + h];
  btT[h * L_SEQ + l] = 1.f / (1.f + expf(-b));
  float dtv = a + dt_bias[h];
  dtv = (dtv > 20.f) ? dtv : log1pf(expf(dtv));
  gT[h * L_SEQ + l] = -expf(A_log[h]) * dtv;
}

// ---- merged prep2 (R18-exact) ----
__global__ __launch_bounds__(256) void prep2_kernel(const float* __restrict__ qkvz,
                                                    const float* __restrict__ cw,
                                                    float* __restrict__ qn,
                                                    float* __restrict__ kn,
                                                    float* __restrict__ vT) {
  __shared__ float tile[32][33];
  const int bid = blockIdx.x;
  if (bid < 4096) {
    int wid = bid * 4 + (threadIdx.x >> 6);
    int lane = threadIdx.x & 63;
    int l = wid >> 4, h = wid & 15;
    const int cq = h * 128 + lane * 2;
    const int ck = KEYD + cq;
    const float* row0 = qkvz + (size_t)l * QZD;
    f32x4 wq0 = *(const f32x4*)&cw[cq * 4];
    f32x4 wq1 = *(const f32x4*)&cw[(cq + 1) * 4];
    f32x4 wk0 = *(const f32x4*)&cw[ck * 4];
    f32x4 wk1 = *(const f32x4*)&cw[(ck + 1) * 4];
    f32x2 xq = *(const f32x2*)&row0[cq];
    f32x2 xk = *(const f32x2*)&row0[ck];
    float q0 = xq[0] * wq0[3], q1 = xq[1] * wq1[3];
    float k0 = xk[0] * wk0[3], k1 = xk[1] * wk1[3];
    if (l >= 1) {
      f32x2 aq = *(const f32x2*)&row0[cq - QZD];
      f32x2 ak = *(const f32x2*)&row0[ck - QZD];
      q0 += aq[0] * wq0[2]; q1 += aq[1] * wq1[2];
      k0 += ak[0] * wk0[2]; k1 += ak[1] * wk1[2];
    }
    if (l >= 2) {
      f32x2 aq = *(const f32x2*)&row0[cq - 2 * QZD];
      f32x2 ak = *(const f32x2*)&row0[ck - 2 * QZD];
      q0 += aq[0] * wq0[1]; q1 += aq[1] * wq1[1];
      k0 += ak[0] * wk0[1]; k1 += ak[1] * wk1[1];
    }
    if (l >= 3) {
      f32x2 aq = *(const f32x2*)&row0[cq - 3 * QZD];
      f32x2 ak = *(const f32x2*)&row0[ck - 3 * QZD];
      q0 += aq[0] * wq0[0]; q1 += aq[1] * wq1[0];
      k0 += ak[0] * wk0[0]; k1 += ak[1] * wk1[0];
    }
    f32x2 qv = { q0 / (1.f + expf(-q0)), q1 / (1.f + expf(-q1)) };
    f32x2 kv = { k0 / (1.f + expf(-k0)), k1 / (1.f + expf(-k1)) };

    float ssq = qv[0] * qv[0] + qv[1] * qv[1];
    float ssk = kv[0] * kv[0] + kv[1] * kv[1];
#pragma unroll
    for (int s = 1; s < 64; s <<= 1) {
      ssq += __shfl_xor(ssq, s);
      ssk += __shfl_xor(ssk, s);
    }
    float scq = 0.08838834764831845f / sqrtf(ssq + 1e-6f);
    float sck = 1.f / sqrtf(ssk + 1e-6f);
    qv[0] *= scq; qv[1] *= scq;
    kv[0] *= sck; kv[1] *= sck;
    size_t base = ((size_t)h * L_SEQ + l) * 128 + lane * 2;
    *(f32x2*)&qn[base] = qv;
    *(f32x2*)&kn[base] = kv;
    return;
  }
  int t = bid - 4096;
  int c0 = (t & 63) * 32, l0 = (t >> 6) * 32;
  int tx = threadIdx.x & 31, ty = threadIdx.x >> 5;
  const int c = 2 * KEYD + c0 + tx;
  f32x4 w = *(const f32x4*)&cw[c * 4];
#pragma unroll
  for (int j = 0; j < 4; ++j) {
    int l = l0 + ty + j * 8;
    const float* p = qkvz + (size_t)l * QZD + c;
    float s = p[0] * w[3];
    if (l >= 1) s += p[-QZD] * w[2];
    if (l >= 2) s += p[-2 * QZD] * w[1];
    if (l >= 3) s += p[-3 * QZD] * w[0];
    tile[ty + j * 8][tx] = s / (1.f + expf(-s));
  }
  __syncthreads();
#pragma unroll
  for (int j = 0; j < 4; ++j)
    vT[(size_t)(c0 + ty + j * 8) * L_SEQ + l0 + tx] = tile[tx][ty + j * 8];
}

// ---------------- winv: per (chunk,head) W = (I+N)^-1, fully parallel ----------
// N[t][s] = beta_t * exp(Gh_t - Gh_s) * (k_t.k_s), s<t. S via MFMA (opass recipe).
// Output Wg[(c*16+h)*4096 + j*64 + s] = W[s][j]  (so WldsT[s][t]=Wg[s*64+t]=W[t][s]).
__global__ __launch_bounds__(256) void winv_kernel(const float* __restrict__ kn,
                                                   const float* __restrict__ gT,
                                                   const float* __restrict__ btT,
                                                   float* __restrict__ Wg) {
  __shared__ alignas(16) u16 kb[64][136];
  __shared__ float Nl[64][65];
  __shared__ float gsh[64], Gh[64], bts[64];

  const int tid = threadIdx.x;
  const int lane = tid & 63, wave = tid >> 6;
  const int l15 = lane & 15, lhi = lane >> 4;
  const int h = blockIdx.x & 15, sc = blockIdx.x >> 4;
  const int l0 = sc * SCH;

  {  // load k chunk f32 -> bf16 LDS (opass pattern)
    int t = tid >> 2, c0 = (tid & 3) * 32;
    const float* kr = kn + ((size_t)h * L_SEQ + l0 + t) * 128 + c0;
#pragma unroll
    for (int j = 0; j < 8; ++j) {
      f32x4 vk = *(const f32x4*)&kr[j * 4];
      u16x4 ok = { f2bf(vk[0]), f2bf(vk[1]), f2bf(vk[2]), f2bf(vk[3]) };
      *(u16x4*)&kb[t][c0 + j * 4] = ok;
    }
  }
  if (tid < 64) {
    gsh[tid] = gT[h * L_SEQ + l0 + tid];
    bts[tid] = btT[h * L_SEQ + l0 + tid];
  }
  __syncthreads();
  if (tid < 64) {
    float a = 0.f;
    for (int u = 0; u <= tid; ++u) a += gsh[u];
    Gh[tid] = a;
  }
  __syncthreads();

  // S = K @ K^T (64x64, K=128): 4 waves, 32x32 quadrants (opass phase-1 recipe)
  f32x4 acc1[2][2] = {};
  const int wm = wave >> 1, wn = wave & 1;
#pragma unroll
  for (int kk = 0; kk < 128; kk += 32) {
    const int koff = kk + lhi * 8;
    bf16x8 a[2], b[2];
#pragma unroll
    for (int m = 0; m < 2; ++m)
      a[m] = *(const bf16x8*)&kb[wm * 32 + m * 16 + l15][koff];
#pragma unroll
    for (int n = 0; n < 2; ++n)
      b[n] = *(const bf16x8*)&kb[wn * 32 + n * 16 + l15][koff];
#pragma unroll
    for (int m = 0; m < 2; ++m)
#pragma unroll
      for (int n = 0; n < 2; ++n)
        acc1[m][n] = __builtin_amdgcn_mfma_f32_16x16x32_bf16(a[m], b[n], acc1[m][n], 0, 0, 0);
  }
#pragma unroll
  for (int m = 0; m < 2; ++m)
#pragma unroll
    for (int n = 0; n < 2; ++n)
#pragma unroll
      for (int j = 0; j < 4; ++j) {
        int t = wm * 32 + m * 16 + lhi * 4 + j;
        int s = wn * 32 + n * 16 + l15;
        Nl[t][s] = (s < t) ? bts[t] * expf(Gh[t] - Gh[s]) * acc1[m][n][j] : 0.f;
      }
  __syncthreads();

  // forward substitution: W[t][j] = d_tj - sum_{s<t} N[t][s] W[s][j]
  // wave 0 only; lane j owns column j, history in registers (static indices).
  if (wave == 0) {
    float w[64];
    w[0] = (lane == 0) ? 1.f : 0.f;
#pragma unroll
    for (int t = 1; t < 64; ++t) {
      float a0 = (lane == t) ? 1.f : 0.f, a1 = 0.f;
#pragma unroll
      for (int s = 0; s + 1 < t; s += 2) {
        a0 = fmaf(-Nl[t][s], w[s], a0);
        a1 = fmaf(-Nl[t][s + 1], w[s + 1], a1);
      }
      if (t & 1) a0 = fmaf(-Nl[t][t - 1], w[t - 1], a0);
      w[t] = a0 + a1;
    }
    size_t base = (size_t)(sc * 16 + h) * 4096 + (size_t)lane * 64;
#pragma unroll
    for (int s = 0; s < 64; ++s) Wg[base + s] = w[s];
  }
}

// ---------------- wyscan: serial over 16 chunks, parallel over (h, 8-dv slab) ----
// Per chunk: r = beta(v - e^Gh K@M_in); delta = W@r; M = e^G63 M + K^T@(decayed delta).
// All f32 VALU; conflict-free LDS layouts. Writes DbT + Mb (opass-compatible).
__global__ __launch_bounds__(256) void wyscan_kernel(const float* __restrict__ kn,
                                                     const float* __restrict__ vT,
                                                     const float* __restrict__ gT,
                                                     const float* __restrict__ btT,
                                                     const float* __restrict__ Wg,
                                                     float* __restrict__ Mb,
                                                     float* __restrict__ DbT) {
  __shared__ float klds[128][65];   // [dk][t]
  __shared__ float Mlds[128][9];    // [dk][dv]
  __shared__ float WldsT[64][65];   // [s][t] = W[t][s]
  __shared__ float rlds[64][9];
  __shared__ float dlds[64][9];
  __shared__ float gsh[64], Gh[64], bts[64];

  const int tid = threadIdx.x;
  const int lane = tid & 63, wave = tid >> 6;
  const int h = blockIdx.x & 15, dvb = blockIdx.x >> 4;  // 16 slabs of 8 dv
  const int dv0 = dvb * 8;
  const int dva = wave * 2, dvb2 = wave * 2 + 1;

  for (int i = tid; i < 128 * 9; i += 256) Mlds[i / 9][i % 9] = 0.f;
  __syncthreads();

#pragma unroll 1
  for (int c = 0; c < NSC; ++c) {
    const int l0 = c * SCH;
    {  // k chunk -> klds[dk][t]
      int t = tid >> 2, c0 = (tid & 3) * 32;
      const float* kr = kn + ((size_t)h * L_SEQ + l0 + t) * 128 + c0;
#pragma unroll
      for (int j = 0; j < 32; ++j) klds[c0 + j][t] = kr[j];
    }
    {  // W -> WldsT (linear copy)
      size_t base = (size_t)(c * 16 + h) * 4096;
      for (int i = tid; i < 4096; i += 256) WldsT[i >> 6][i & 63] = Wg[base + i];
    }
    if (tid < 64) {
      gsh[tid] = gT[h * L_SEQ + l0 + tid];
      bts[tid] = btT[h * L_SEQ + l0 + tid];
    }
    {  // Mb dump: M_in at l0 (reads previous chunk's final Mlds)
      int dv = tid >> 5, dk0 = (tid & 31) * 4;
      float* mr = Mb + (((size_t)(c * 16 + h)) * 128 + dv0 + dv) * 128 + dk0;
#pragma unroll
      for (int j = 0; j < 4; ++j) mr[j] = Mlds[dk0 + j][dv];
    }
    __syncthreads();
    if (tid == 0) {
      float a = 0.f;
      for (int u = 0; u < 64; ++u) { a += gsh[u]; Gh[u] = a; }
    }
    __syncthreads();

    // r phase: lane = t; wave covers dv pair
    {
      const int t = lane;
      float a0 = 0.f, a1 = 0.f;
      for (int dk = 0; dk < 128; ++dk) {
        float kv = klds[dk][t];
        a0 = fmaf(kv, Mlds[dk][dva], a0);
        a1 = fmaf(kv, Mlds[dk][dvb2], a1);
      }
      float egt = expf(Gh[t]);
      float bt = bts[t];
      float v0 = vT[(size_t)(h * 128 + dv0 + dva) * L_SEQ + l0 + t];
      float v1 = vT[(size_t)(h * 128 + dv0 + dvb2) * L_SEQ + l0 + t];
      rlds[t][dva]  = bt * (v0 - egt * a0);
      rlds[t][dvb2] = bt * (v1 - egt * a1);
    }
    __syncthreads();

    // delta phase: delta = W @ r
    {
      const int t = lane;
      float a0 = 0.f, a1 = 0.f;
      for (int s = 0; s < 64; ++s) {
        float wv = WldsT[s][t];
        a0 = fmaf(wv, rlds[s][dva], a0);
        a1 = fmaf(wv, rlds[s][dvb2], a1);
      }
      DbT[(size_t)(h * 128 + dv0 + dva) * L_SEQ + l0 + t]  = a0;
      DbT[(size_t)(h * 128 + dv0 + dvb2) * L_SEQ + l0 + t] = a1;
      float e63t = expf(Gh[63] - Gh[t]);
      dlds[t][dva]  = a0 * e63t;
      dlds[t][dvb2] = a1 * e63t;
    }
    __syncthreads();

    // M update: M = e^G63 * M + K^T @ dlds
    {
      const float E63 = expf(Gh[63]);
#pragma unroll
      for (int rep = 0; rep < 2; ++rep) {
        const int dk = lane + rep * 64;
#pragma unroll
        for (int dvi = 0; dvi < 2; ++dvi) {
          const int dv = wave * 2 + dvi;
          float acc = E63 * Mlds[dk][dv];
          for (int s = 0; s < 64; ++s)
            acc = fmaf(klds[dk][s], dlds[s][dv], acc);
          Mlds[dk][dv] = acc;
        }
      }
    }
    __syncthreads();
  }
}

// ---------------- MFMA output reconstruction + fused gated RMSNorm (R18-exact) ----
__global__ __launch_bounds__(256) void opass_kernel(const float* __restrict__ qn,
                                                    const float* __restrict__ kn,
                                                    const float* __restrict__ DbT,
                                                    const float* __restrict__ gT,
                                                    const float* __restrict__ Mb,
                                                    const float* __restrict__ qkvz,
                                                    const float* __restrict__ norm_w,
                                                    u16* __restrict__ gn) {
  __shared__ alignas(16) u16 qsb[64][136];
  __shared__ alignas(16) u16 bbuf[128][136];
  __shared__ alignas(16) u16 Asb[64][72];
  __shared__ float gsh[64], Gh[64];
  __shared__ float ssr[2][64];

  const int tid = threadIdx.x;
  const int lane = tid & 63, wave = tid >> 6;
  const int l15 = lane & 15, lhi = lane >> 4;
  const int h = blockIdx.x & 15, sc = blockIdx.x >> 4;
  const int l0 = sc * SCH;

  {
    int t = tid >> 2, c0 = (tid & 3) * 32;
    const float* qr = qn + ((size_t)h * L_SEQ + l0 + t) * 128 + c0;
    const float* kr = kn + ((size_t)h * L_SEQ + l0 + t) * 128 + c0;
#pragma unroll
    for (int j = 0; j < 8; ++j) {
      f32x4 vq = *(const f32x4*)&qr[j * 4];
      f32x4 vk = *(const f32x4*)&kr[j * 4];
      u16x4 oq = { f2bf(vq[0]), f2bf(vq[1]), f2bf(vq[2]), f2bf(vq[3]) };
      u16x4 ok = { f2bf(vk[0]), f2bf(vk[1]), f2bf(vk[2]), f2bf(vk[3]) };
      *(u16x4*)&qsb[t][c0 + j * 4] = oq;
      *(u16x4*)&bbuf[t][c0 + j * 4] = ok;
    }
  }
  if (tid < 64) gsh[tid] = gT[h * L_SEQ + l0 + tid];
  __syncthreads();
  if (tid < 64) {
    float a = 0.f;
    for (int u = 0; u <= tid; ++u) a += gsh[u];
    Gh[tid] = a;
  }
  __syncthreads();

  f32x4 acc1[2][2] = {};
  const int wm = wave >> 1, wn = wave & 1;
#pragma unroll
  for (int kk = 0; kk < 128; kk += 32) {
    const int koff = kk + lhi * 8;
    bf16x8 a[2], b[2];
#pragma unroll
    for (int m = 0; m < 2; ++m)
      a[m] = *(const bf16x8*)&qsb[wm * 32 + m * 16 + l15][koff];
#pragma unroll
    for (int n = 0; n < 2; ++n)
      b[n] = *(const bf16x8*)&bbuf[wn * 32 + n * 16 + l15][koff];
#pragma unroll
    for (int m = 0; m < 2; ++m)
#pragma unroll
      for (int n = 0; n < 2; ++n)
        acc1[m][n] = __builtin_amdgcn_mfma_f32_16x16x32_bf16(a[m], b[n], acc1[m][n], 0, 0, 0);
  }
#pragma unroll
  for (int m = 0; m < 2; ++m)
#pragma unroll
    for (int n = 0; n < 2; ++n)
#pragma unroll
      for (int j = 0; j < 4; ++j) {
        int t = wm * 32 + m * 16 + lhi * 4 + j;
        int s = wn * 32 + n * 16 + l15;
        float a = (s <= t) ? acc1[m][n][j] * expf(Gh[t] - Gh[s]) : 0.f;
        Asb[t][s] = f2bf(a);
      }
  __syncthreads();

  {
    int dv = tid >> 1, c0 = (tid & 1) * 64;
    const float* mr = Mb + (((size_t)sc * 16 + h) * 128 + dv) * 128 + c0;
#pragma unroll
    for (int j = 0; j < 16; ++j) {
      f32x4 v = *(const f32x4*)&mr[j * 4];
      u16x4 o = { f2bf(v[0]), f2bf(v[1]), f2bf(v[2]), f2bf(v[3]) };
      *(u16x4*)&bbuf[dv][c0 + j * 4] = o;
    }
  }
  __syncthreads();

  f32x4 acc[2][4] = {};
#pragma unroll
  for (int kk = 0; kk < 128; kk += 32) {
    const int koff = kk + lhi * 8;
    bf16x8 a[2], b[4];
#pragma unroll
    for (int m = 0; m < 2; ++m)
      a[m] = *(const bf16x8*)&qsb[wm * 32 + m * 16 + l15][koff];
#pragma unroll
    for (int n = 0; n < 4; ++n)
      b[n] = *(const bf16x8*)&bbuf[wn * 64 + n * 16 + l15][koff];
#pragma unroll
    for (int m = 0; m < 2; ++m)
#pragma unroll
      for (int n = 0; n < 4; ++n)
        acc[m][n] = __builtin_amdgcn_mfma_f32_16x16x32_bf16(a[m], b[n], acc[m][n], 0, 0, 0);
  }
#pragma unroll
  for (int m = 0; m < 2; ++m) {
#pragma unroll
    for (int j = 0; j < 4; ++j) {
      int t = wm * 32 + m * 16 + lhi * 4 + j;
      float sc1 = expf(Gh[t]);
#pragma unroll
      for (int n = 0; n < 4; ++n) acc[m][n][j] *= sc1;
    }
  }
  __syncthreads();

  {
    int dv = tid >> 1, c0 = (tid & 1) * 32;
    const float* dr = DbT + (size_t)(h * 128 + dv) * L_SEQ + l0 + c0;
#pragma unroll
    for (int j = 0; j < 8; ++j) {
      f32x4 v = *(const f32x4*)&dr[j * 4];
      u16x4 o = { f2bf(v[0]), f2bf(v[1]), f2bf(v[2]), f2bf(v[3]) };
      *(u16x4*)&bbuf[dv][c0 + j * 4] = o;
    }
  }
  __syncthreads();

#pragma unroll
  for (int kk = 0; kk < 64; kk += 32) {
    const int koff = kk + lhi * 8;
    bf16x8 a[2], b[4];
#pragma unroll
    for (int m = 0; m < 2; ++m)
      a[m] = *(const bf16x8*)&Asb[wm * 32 + m * 16 + l15][koff];
#pragma unroll
    for (int n = 0; n < 4; ++n)
      b[n] = *(const bf16x8*)&bbuf[wn * 64 + n * 16 + l15][koff];
#pragma unroll
    for (int m = 0; m < 2; ++m)
#pragma unroll
      for (int n = 0; n < 4; ++n)
        acc[m][n] = __builtin_amdgcn_mfma_f32_16x16x32_bf16(a[m], b[n], acc[m][n], 0, 0, 0);
  }

  float pr[2][4];
#pragma unroll
  for (int m = 0; m < 2; ++m)
#pragma unroll
    for (int j = 0; j < 4; ++j) {
      float p = 0.f;
#pragma unroll
      for (int n = 0; n < 4; ++n) p = fmaf(acc[m][n][j], acc[m][n][j], p);
      pr[m][j] = red16(p);
    }
  if (l15 == 0) {
#pragma unroll
    for (int m = 0; m < 2; ++m)
#pragma unroll
      for (int j = 0; j < 4; ++j)
        ssr[wn][wm * 32 + m * 16 + lhi * 4 + j] = pr[m][j];
  }
  __syncthreads();
#pragma unroll
  for (int m = 0; m < 2; ++m)
#pragma unroll
    for (int j = 0; j < 4; ++j) {
      int t = wm * 32 + m * 16 + lhi * 4 + j;
      float ss = ssr[0][t] + ssr[1][t];
      float r = 1.f / sqrtf(ss * (1.f / 128.f) + 1e-6f);
      const float* zp = qkvz + (size_t)(l0 + t) * QZD + CONVD + h * 128;
      u16* dst = gn + (size_t)(l0 + t) * VALD + h * 128;
#pragma unroll
      for (int n = 0; n < 4; ++n) {
        int dv = wn * 64 + n * 16 + l15;
        float z = zp[dv];
        float sil = z / (1.f + expf(-z));
        dst[dv] = f2bf(acc[m][n][j] * r * norm_w[dv] * sil);
      }
    }
}

extern "C" void kernel_launch(void* const* d_in, const int* in_sizes, int n_in,
                              void* d_out, int out_size, void* d_ws, size_t ws_size,
                              hipStream_t stream) {
  const float* x      = (const float*)d_in[0];
  const float* Wqkv   = (const float*)d_in[1];
  const float* Wz     = (const float*)d_in[2];
  const float* Wb     = (const float*)d_in[3];
  const float* Wa     = (const float*)d_in[4];
  const float* conv_w = (const float*)d_in[5];
  const float* A_log  = (const float*)d_in[6];
  const float* dt_bias= (const float*)d_in[7];
  const float* norm_w = (const float*)d_in[8];
  const float* Wout   = (const float*)d_in[9];
  float* out = (float*)d_out;

  char* ws = (char*)d_ws;
  size_t off = 0;
  auto alloc = [&](size_t bytes) {
    void* p = ws + off;
    off = (off + bytes + 255) & ~(size_t)255;
    return p;
  };
  u16* xb     = (u16*)alloc((size_t)L_SEQ * IDIM_ * 2);
  u16* WcatT  = (u16*)alloc((size_t)QZD * IDIM_ * 2);
  u16* WoutT  = (u16*)alloc((size_t)IDIM_ * VALD * 2);
  float* qkvz = (float*)alloc((size_t)L_SEQ * QZD * 4);
  float* qn   = (float*)alloc((size_t)H_ * L_SEQ * 128 * 4);
  float* kn   = (float*)alloc((size_t)H_ * L_SEQ * 128 * 4);
  float* vT   = (float*)alloc((size_t)H_ * 128 * L_SEQ * 4);
  float* btT  = (float*)alloc((size_t)L_SEQ * H_ * 4);
  float* gTb  = (float*)alloc((size_t)L_SEQ * H_ * 4);
  float* Wgb  = (float*)alloc((size_t)NSC * H_ * 64 * 64 * 4);    // 4MB
  float* Mb   = (float*)alloc((size_t)NSC * H_ * 128 * 128 * 4);  // 16MB
  float* DbT  = (float*)alloc((size_t)H_ * 128 * L_SEQ * 4);      // 8MB
  u16* gn     = (u16*)alloc((size_t)L_SEQ * VALD * 2);

  // merged casts/transposes + gate-weight rows + zero pad (1 launch)
  prepcast_kernel<<<22616, 256, 0, stream>>>(x, Wqkv, Wz, Wb, Wa, Wout, xb, WcatT, WoutT);

  // combined projection [qkv | z | gates]
  gemm_bt_kernel<<<dim3(QZD / 128, L_SEQ / 128), 256, 0, stream>>>(xb, WcatT, qkvz, L_SEQ, QZD, IDIM_);

  // gates
  gatelite_kernel<<<64, 256, 0, stream>>>(qkvz, A_log, dt_bias, btT, gTb);

  // merged prep2
  prep2_kernel<<<6144, 256, 0, stream>>>(qkvz, conv_w, qn, kn, vT);

  // chunked-WY scan: W precompute (parallel) + 16-step chunk recurrence
  winv_kernel<<<NSC * H_, 256, 0, stream>>>(kn, gTb, btT, Wgb);
  wyscan_kernel<<<256, 256, 0, stream>>>(kn, vT, gTb, btT, Wgb, Mb, DbT);

  // MFMA output reconstruction + fused gated RMSNorm
  opass_kernel<<<NSC * H_, 256, 0, stream>>>(qn, kn, DbT, gTb, Mb, qkvz, norm_w, gn);

  // final projection
  gemm_bt64_kernel<<<256, 256, 0, stream>>>(gn, WoutT, out, L_SEQ, IDIM_, VALD, 1);
}

// Round 20
// 362.794 us; speedup vs baseline: 1.0011x; 1.0011x over previous
//
#include <hip/hip_runtime.h>

typedef short bf16x8 __attribute__((ext_vector_type(8)));
typedef float f32x4 __attribute__((ext_vector_type(4)));
typedef float f32x2 __attribute__((ext_vector_type(2)));
typedef unsigned short u16;
typedef u16 u16x4 __attribute__((ext_vector_type(4)));

#define L_SEQ 1024
#define IDIM_ 2048
#define H_ 16
#define DK_ 128
#define DV_ 128
#define KEYD 2048
#define VALD 2048
#define CONVD 6144
#define QZD 8320          // qkv(6144) | z(2048) | b(16) | a(16) | pad(96)
#define GCOL 8192
#define SCH 64
#define NSC (L_SEQ / SCH)

__device__ __forceinline__ u16 f2bf(float f) {
  union { float f; unsigned u; } v; v.f = f;
  unsigned r = v.u + 0x7FFF + ((v.u >> 16) & 1);  // RNE
  return (u16)(r >> 16);
}

// 16-lane allreduce, all-DPP. Verified R3-R19.
__device__ __forceinline__ float red16(float x) {
  union U { float f; int i; } a, t;
  a.f = x;
  t.i = __builtin_amdgcn_update_dpp(0, a.i, 0xB1, 0xF, 0xF, true); a.f += t.f;
  t.i = __builtin_amdgcn_update_dpp(0, a.i, 0x4E, 0xF, 0xF, true); a.f += t.f;
  t.i = __builtin_amdgcn_update_dpp(0, a.i, 0x141, 0xF, 0xF, true); a.f += t.f;
  t.i = __builtin_amdgcn_update_dpp(0, a.i, 0x140, 0xF, 0xF, true); a.f += t.f;
  return a.f;
}

// ---- merged cast/transpose prep (R18-exact) ----
__global__ __launch_bounds__(256) void prepcast_kernel(const float* __restrict__ x,
                                                       const float* __restrict__ Wqkv,
                                                       const float* __restrict__ Wz,
                                                       const float* __restrict__ Wb,
                                                       const float* __restrict__ Wa,
                                                       const float* __restrict__ Wout,
                                                       u16* __restrict__ xb,
                                                       u16* __restrict__ WcatT,
                                                       u16* __restrict__ WoutT) {
  __shared__ float tile[32][33];
  const int bid = blockIdx.x;
  if (bid < 2048) {
    int i = (bid * 256 + threadIdx.x) * 4;
    f32x4 v = *(const f32x4*)&x[i];
    u16x4 o = { f2bf(v[0]), f2bf(v[1]), f2bf(v[2]), f2bf(v[3]) };
    *(u16x4*)&xb[i] = o;
    return;
  }
  if (bid >= 22592) {
    size_t off = (size_t)8224 * IDIM_ + (size_t)(bid - 22592) * 8192 + threadIdx.x * 32;
    u16x4 z = {0, 0, 0, 0};
#pragma unroll
    for (int j = 0; j < 8; ++j) *(u16x4*)&WcatT[off + j * 4] = z;
    return;
  }
  if (bid >= 22528) {
    int by = bid - 22528;
    int r = threadIdx.x >> 3, c8 = threadIdx.x & 7;
    int row = by * 32 + r;
#pragma unroll
    for (int cc = 0; cc < 2; ++cc) {
      int c = cc * 8 + c8;
      WcatT[(size_t)(GCOL + c) * IDIM_ + row]      = f2bf(Wb[(size_t)row * 16 + c]);
      WcatT[(size_t)(GCOL + 16 + c) * IDIM_ + row] = f2bf(Wa[(size_t)row * 16 + c]);
    }
    return;
  }
  const float* W; u16* WT; int R, C, bx, by;
  if (bid < 14336) {
    int t = bid - 2048;  bx = t % 192; by = t / 192;
    W = Wqkv; WT = WcatT; R = IDIM_; C = CONVD;
  } else if (bid < 18432) {
    int t = bid - 14336; bx = t & 63; by = t >> 6;
    W = Wz; WT = WcatT + (size_t)CONVD * IDIM_; R = IDIM_; C = VALD;
  } else {
    int t = bid - 18432; bx = t & 63; by = t >> 6;
    W = Wout; WT = WoutT; R = VALD; C = IDIM_;
  }
  int c0 = bx * 32, r0 = by * 32;
  int tx = threadIdx.x & 31, ty = threadIdx.x >> 5;
#pragma unroll
  for (int j = 0; j < 4; ++j)
    tile[ty + j * 8][tx] = W[(size_t)(r0 + ty + j * 8) * C + c0 + tx];
  __syncthreads();
#pragma unroll
  for (int j = 0; j < 4; ++j)
    WT[(size_t)(c0 + ty + j * 8) * R + r0 + tx] = f2bf(tile[tx][ty + j * 8]);
}

// ---------------- NT GEMM (R18-exact) ----------------
__global__ __launch_bounds__(256) void gemm_bt_kernel(const u16* __restrict__ A,
                                                      const u16* __restrict__ B,
                                                      float* __restrict__ C,
                                                      int M, int N, int K) {
  __shared__ short As[128 * 72];
  __shared__ short Bs[128 * 72];
  const int tid = threadIdx.x;
  const int lane = tid & 63, wave = tid >> 6;
  const int wm = wave >> 1, wn = wave & 1;
  const int m0 = blockIdx.y * 128, n0 = blockIdx.x * 128;
  const int l15 = lane & 15, lhi = lane >> 4;

  f32x4 acc[4][4] = {};

  for (int k0 = 0; k0 < K; k0 += 64) {
    __syncthreads();
#pragma unroll
    for (int i = 0; i < 4; ++i) {
      int chunk = tid + i * 256;
      int row = chunk >> 3;
      int kc = (chunk & 7) * 8;
      *(bf16x8*)&As[row * 72 + kc] =
          *(const bf16x8*)&A[(size_t)(m0 + row) * K + k0 + kc];
      *(bf16x8*)&Bs[row * 72 + kc] =
          *(const bf16x8*)&B[(size_t)(n0 + row) * K + k0 + kc];
    }
    __syncthreads();
#pragma unroll
    for (int kk = 0; kk < 64; kk += 32) {
      const int koff = kk + lhi * 8;
      bf16x8 a[4], b[4];
#pragma unroll
      for (int m = 0; m < 4; ++m)
        a[m] = *(const bf16x8*)&As[(wm * 64 + m * 16 + l15) * 72 + koff];
#pragma unroll
      for (int n = 0; n < 4; ++n)
        b[n] = *(const bf16x8*)&Bs[(wn * 64 + n * 16 + l15) * 72 + koff];
#pragma unroll
      for (int m = 0; m < 4; ++m)
#pragma unroll
        for (int n = 0; n < 4; ++n)
          acc[m][n] = __builtin_amdgcn_mfma_f32_16x16x32_bf16(a[m], b[n], acc[m][n], 0, 0, 0);
    }
  }
#pragma unroll
  for (int m = 0; m < 4; ++m)
#pragma unroll
    for (int n = 0; n < 4; ++n)
#pragma unroll
      for (int j = 0; j < 4; ++j) {
        int row = m0 + wm * 64 + m * 16 + lhi * 4 + j;
        int col = n0 + wn * 64 + n * 16 + l15;
        C[(size_t)row * N + col] = acc[m][n][j];
      }
}

// ---------------- NT GEMM BM=64 (R18-exact) ----------------
__global__ __launch_bounds__(256) void gemm_bt64_kernel(const u16* __restrict__ A,
                                                        const u16* __restrict__ B,
                                                        float* __restrict__ C,
                                                        int M, int N, int K, int cxl) {
  __shared__ short As[64 * 72];
  __shared__ short Bs[128 * 72];
  const int tid = threadIdx.x;
  const int lane = tid & 63, wave = tid >> 6;
  const int wm = wave >> 1, wn = wave & 1;
  const int bid = blockIdx.x;
  const int xcd = bid & 7, bi = bid >> 3;
  const int bx = (xcd << cxl) + (bi & ((1 << cxl) - 1));
  const int by = bi >> cxl;
  const int m0 = by * 64, n0 = bx * 128;
  const int l15 = lane & 15, lhi = lane >> 4;

  f32x4 acc[2][4] = {};

  for (int k0 = 0; k0 < K; k0 += 64) {
    __syncthreads();
#pragma unroll
    for (int i = 0; i < 2; ++i) {
      int chunk = tid + i * 256;
      int row = chunk >> 3;
      int kc = (chunk & 7) * 8;
      *(bf16x8*)&As[row * 72 + kc] =
          *(const bf16x8*)&A[(size_t)(m0 + row) * K + k0 + kc];
    }
#pragma unroll
    for (int i = 0; i < 4; ++i) {
      int chunk = tid + i * 256;
      int row = chunk >> 3;
      int kc = (chunk & 7) * 8;
      *(bf16x8*)&Bs[row * 72 + kc] =
          *(const bf16x8*)&B[(size_t)(n0 + row) * K + k0 + kc];
    }
    __syncthreads();
#pragma unroll
    for (int kk = 0; kk < 64; kk += 32) {
      const int koff = kk + lhi * 8;
      bf16x8 a[2], b[4];
#pragma unroll
      for (int m = 0; m < 2; ++m)
        a[m] = *(const bf16x8*)&As[(wm * 32 + m * 16 + l15) * 72 + koff];
#pragma unroll
      for (int n = 0; n < 4; ++n)
        b[n] = *(const bf16x8*)&Bs[(wn * 64 + n * 16 + l15) * 72 + koff];
#pragma unroll
      for (int m = 0; m < 2; ++m)
#pragma unroll
        for (int n = 0; n < 4; ++n)
          acc[m][n] = __builtin_amdgcn_mfma_f32_16x16x32_bf16(a[m], b[n], acc[m][n], 0, 0, 0);
    }
  }
#pragma unroll
  for (int m = 0; m < 2; ++m)
#pragma unroll
    for (int n = 0; n < 4; ++n)
#pragma unroll
      for (int j = 0; j < 4; ++j) {
        int row = m0 + wm * 32 + m * 16 + lhi * 4 + j;
        int col = n0 + wn * 64 + n * 16 + l15;
        C[(size_t)row * N + col] = acc[m][n][j];
      }
}

// -------- gatelite (R19-exact) --------
__global__ __launch_bounds__(256) void gatelite_kernel(const float* __restrict__ qkvz,
                                                       const float* __restrict__ A_log,
                                                       const float* __restrict__ dt_bias,
                                                       float* __restrict__ btT,
                                                       float* __restrict__ gT) {
  int gid = blockIdx.x * 256 + threadIdx.x;
  int l = gid >> 4, h = gid & 15;
  const float* row = qkvz + (size_t)l * QZD + GCOL;
  float b = row[h], a = row[16 + h];
  btT[h * L_SEQ + l] = 1.f / (1.f + expf(-b));
  float dtv = a + dt_bias[h];
  dtv = (dtv > 20.f) ? dtv : log1pf(expf(dtv));
  gT[h * L_SEQ + l] = -expf(A_log[h]) * dtv;
}

// ---- merged prep2 (R19-exact) ----
__global__ __launch_bounds__(256) void prep2_kernel(const float* __restrict__ qkvz,
                                                    const float* __restrict__ cw,
                                                    float* __restrict__ qn,
                                                    float* __restrict__ kn,
                                                    float* __restrict__ vT) {
  __shared__ float tile[32][33];
  const int bid = blockIdx.x;
  if (bid < 4096) {
    int wid = bid * 4 + (threadIdx.x >> 6);
    int lane = threadIdx.x & 63;
    int l = wid >> 4, h = wid & 15;
    const int cq = h * 128 + lane * 2;
    const int ck = KEYD + cq;
    const float* row0 = qkvz + (size_t)l * QZD;
    f32x4 wq0 = *(const f32x4*)&cw[cq * 4];
    f32x4 wq1 = *(const f32x4*)&cw[(cq + 1) * 4];
    f32x4 wk0 = *(const f32x4*)&cw[ck * 4];
    f32x4 wk1 = *(const f32x4*)&cw[(ck + 1) * 4];
    f32x2 xq = *(const f32x2*)&row0[cq];
    f32x2 xk = *(const f32x2*)&row0[ck];
    float q0 = xq[0] * wq0[3], q1 = xq[1] * wq1[3];
    float k0 = xk[0] * wk0[3], k1 = xk[1] * wk1[3];
    if (l >= 1) {
      f32x2 aq = *(const f32x2*)&row0[cq - QZD];
      f32x2 ak = *(const f32x2*)&row0[ck - QZD];
      q0 += aq[0] * wq0[2]; q1 += aq[1] * wq1[2];
      k0 += ak[0] * wk0[2]; k1 += ak[1] * wk1[2];
    }
    if (l >= 2) {
      f32x2 aq = *(const f32x2*)&row0[cq - 2 * QZD];
      f32x2 ak = *(const f32x2*)&row0[ck - 2 * QZD];
      q0 += aq[0] * wq0[1]; q1 += aq[1] * wq1[1];
      k0 += ak[0] * wk0[1]; k1 += ak[1] * wk1[1];
    }
    if (l >= 3) {
      f32x2 aq = *(const f32x2*)&row0[cq - 3 * QZD];
      f32x2 ak = *(const f32x2*)&row0[ck - 3 * QZD];
      q0 += aq[0] * wq0[0]; q1 += aq[1] * wq1[0];
      k0 += ak[0] * wk0[0]; k1 += ak[1] * wk1[0];
    }
    f32x2 qv = { q0 / (1.f + expf(-q0)), q1 / (1.f + expf(-q1)) };
    f32x2 kv = { k0 / (1.f + expf(-k0)), k1 / (1.f + expf(-k1)) };

    float ssq = qv[0] * qv[0] + qv[1] * qv[1];
    float ssk = kv[0] * kv[0] + kv[1] * kv[1];
#pragma unroll
    for (int s = 1; s < 64; s <<= 1) {
      ssq += __shfl_xor(ssq, s);
      ssk += __shfl_xor(ssk, s);
    }
    float scq = 0.08838834764831845f / sqrtf(ssq + 1e-6f);
    float sck = 1.f / sqrtf(ssk + 1e-6f);
    qv[0] *= scq; qv[1] *= scq;
    kv[0] *= sck; kv[1] *= sck;
    size_t base = ((size_t)h * L_SEQ + l) * 128 + lane * 2;
    *(f32x2*)&qn[base] = qv;
    *(f32x2*)&kn[base] = kv;
    return;
  }
  int t = bid - 4096;
  int c0 = (t & 63) * 32, l0 = (t >> 6) * 32;
  int tx = threadIdx.x & 31, ty = threadIdx.x >> 5;
  const int c = 2 * KEYD + c0 + tx;
  f32x4 w = *(const f32x4*)&cw[c * 4];
#pragma unroll
  for (int j = 0; j < 4; ++j) {
    int l = l0 + ty + j * 8;
    const float* p = qkvz + (size_t)l * QZD + c;
    float s = p[0] * w[3];
    if (l >= 1) s += p[-QZD] * w[2];
    if (l >= 2) s += p[-2 * QZD] * w[1];
    if (l >= 3) s += p[-3 * QZD] * w[0];
    tile[ty + j * 8][tx] = s / (1.f + expf(-s));
  }
  __syncthreads();
#pragma unroll
  for (int j = 0; j < 4; ++j)
    vT[(size_t)(c0 + ty + j * 8) * L_SEQ + l0 + tx] = tile[tx][ty + j * 8];
}

// ---------------- winv (R19-exact, verified passing) ----------
__global__ __launch_bounds__(256) void winv_kernel(const float* __restrict__ kn,
                                                   const float* __restrict__ gT,
                                                   const float* __restrict__ btT,
                                                   float* __restrict__ Wg) {
  __shared__ alignas(16) u16 kb[64][136];
  __shared__ float Nl[64][65];
  __shared__ float gsh[64], Gh[64], bts[64];

  const int tid = threadIdx.x;
  const int lane = tid & 63, wave = tid >> 6;
  const int l15 = lane & 15, lhi = lane >> 4;
  const int h = blockIdx.x & 15, sc = blockIdx.x >> 4;
  const int l0 = sc * SCH;

  {
    int t = tid >> 2, c0 = (tid & 3) * 32;
    const float* kr = kn + ((size_t)h * L_SEQ + l0 + t) * 128 + c0;
#pragma unroll
    for (int j = 0; j < 8; ++j) {
      f32x4 vk = *(const f32x4*)&kr[j * 4];
      u16x4 ok = { f2bf(vk[0]), f2bf(vk[1]), f2bf(vk[2]), f2bf(vk[3]) };
      *(u16x4*)&kb[t][c0 + j * 4] = ok;
    }
  }
  if (tid < 64) {
    gsh[tid] = gT[h * L_SEQ + l0 + tid];
    bts[tid] = btT[h * L_SEQ + l0 + tid];
  }
  __syncthreads();
  if (tid < 64) {
    float a = 0.f;
    for (int u = 0; u <= tid; ++u) a += gsh[u];
    Gh[tid] = a;
  }
  __syncthreads();

  f32x4 acc1[2][2] = {};
  const int wm = wave >> 1, wn = wave & 1;
#pragma unroll
  for (int kk = 0; kk < 128; kk += 32) {
    const int koff = kk + lhi * 8;
    bf16x8 a[2], b[2];
#pragma unroll
    for (int m = 0; m < 2; ++m)
      a[m] = *(const bf16x8*)&kb[wm * 32 + m * 16 + l15][koff];
#pragma unroll
    for (int n = 0; n < 2; ++n)
      b[n] = *(const bf16x8*)&kb[wn * 32 + n * 16 + l15][koff];
#pragma unroll
    for (int m = 0; m < 2; ++m)
#pragma unroll
      for (int n = 0; n < 2; ++n)
        acc1[m][n] = __builtin_amdgcn_mfma_f32_16x16x32_bf16(a[m], b[n], acc1[m][n], 0, 0, 0);
  }
#pragma unroll
  for (int m = 0; m < 2; ++m)
#pragma unroll
    for (int n = 0; n < 2; ++n)
#pragma unroll
      for (int j = 0; j < 4; ++j) {
        int t = wm * 32 + m * 16 + lhi * 4 + j;
        int s = wn * 32 + n * 16 + l15;
        Nl[t][s] = (s < t) ? bts[t] * expf(Gh[t] - Gh[s]) * acc1[m][n][j] : 0.f;
      }
  __syncthreads();

  if (wave == 0) {
    float w[64];
    w[0] = (lane == 0) ? 1.f : 0.f;
#pragma unroll
    for (int t = 1; t < 64; ++t) {
      float a0 = (lane == t) ? 1.f : 0.f, a1 = 0.f;
#pragma unroll
      for (int s = 0; s + 1 < t; s += 2) {
        a0 = fmaf(-Nl[t][s], w[s], a0);
        a1 = fmaf(-Nl[t][s + 1], w[s + 1], a1);
      }
      if (t & 1) a0 = fmaf(-Nl[t][t - 1], w[t - 1], a0);
      w[t] = a0 + a1;
    }
    size_t base = (size_t)(sc * 16 + h) * 4096 + (size_t)lane * 64;
#pragma unroll
    for (int s = 0; s < 64; ++s) Wg[base + s] = w[s];
  }
}

// ---------------- wyscan v2: MFMA chunk recurrence, 1 block per head ----------
// Serial over 16 chunks; per chunk three MFMA matmuls (verified fragment recipes):
//   KM = K@M_in (opass-phase-3 shape), delta = W@r (opass-phase-2 shape),
//   M = E63*M + K^T@deltadecayed (gemm_bt 4x4 wave-tile shape).
// f32 M master in registers; bf16 only on MFMA operands.
__global__ __launch_bounds__(256) void wyscan_kernel(const float* __restrict__ kn,
                                                     const float* __restrict__ vT,
                                                     const float* __restrict__ gT,
                                                     const float* __restrict__ btT,
                                                     const float* __restrict__ Wg,
                                                     float* __restrict__ Mb,
                                                     float* __restrict__ DbT) {
  __shared__ alignas(16) u16 kb[64][136];     // A for KM: kb[t][dk]
  __shared__ alignas(16) u16 kbT[128][72];    // A for M-upd: kbT[dk][s]
  __shared__ alignas(16) u16 Wbf[64][72];     // A for delta: W[t][s]
  __shared__ alignas(16) u16 rTb[128][72];    // B for delta: r^T[dv][s]
  __shared__ alignas(16) u16 ddT[128][72];    // B for M-upd: deltadec^T[dv][s]
  __shared__ alignas(16) u16 MbfT[128][136];  // B for KM: M^T[dv][dk]
  __shared__ float gsh[64], Gh[64], bts[64];

  const int tid = threadIdx.x;
  const int lane = tid & 63, wave = tid >> 6;
  const int l15 = lane & 15, lhi = lane >> 4;
  const int wm = wave >> 1, wn = wave & 1;
  const int h = blockIdx.x;

  for (int i = tid; i < 128 * 136; i += 256) (&MbfT[0][0])[i] = 0;
  f32x4 Mreg[4][4];
#pragma unroll
  for (int m = 0; m < 4; ++m)
#pragma unroll
    for (int n = 0; n < 4; ++n) Mreg[m][n] = (f32x4){0.f, 0.f, 0.f, 0.f};
  __syncthreads();

#pragma unroll 1
  for (int c = 0; c < NSC; ++c) {
    const int l0 = c * SCH;
    // dump M_in (chunk-entry state) to Mb  [(c*16+h)*128+dv]*128+dk
#pragma unroll
    for (int m = 0; m < 4; ++m)
#pragma unroll
      for (int n = 0; n < 4; ++n) {
        int dv = wn * 64 + n * 16 + l15;
        int dk0 = wm * 64 + m * 16 + lhi * 4;
        *(f32x4*)&Mb[(((size_t)(c * 16 + h)) * 128 + dv) * 128 + dk0] = Mreg[m][n];
      }
    // stage k (both layouts), W (transposed read), gates
    {
      int t = tid >> 2, c0 = (tid & 3) * 32;
      const float* kr = kn + ((size_t)h * L_SEQ + l0 + t) * 128 + c0;
#pragma unroll
      for (int j = 0; j < 32; ++j) {
        u16 kv = f2bf(kr[j]);
        kb[t][c0 + j] = kv;
        kbT[c0 + j][t] = kv;
      }
    }
    {
      // Wbf[t][s] = W[t][s] = Wg[base + s*64 + t]
      int t = tid >> 2, s0 = (tid & 3) * 16;
      size_t base = (size_t)(c * 16 + h) * 4096;
#pragma unroll
      for (int i = 0; i < 16; ++i)
        Wbf[t][s0 + i] = f2bf(Wg[base + (size_t)(s0 + i) * 64 + t]);
    }
    if (tid < 64) {
      gsh[tid] = gT[h * L_SEQ + l0 + tid];
      bts[tid] = btT[h * L_SEQ + l0 + tid];
    }
    __syncthreads();
    if (tid < 64) {
      float a = 0.f;
      for (int u = 0; u <= tid; ++u) a += gsh[u];
      Gh[tid] = a;
    }
    __syncthreads();

    // ---- KM = K @ M_in (64x128, K=128); r = beta(v - e^Gh KM) -> rTb bf16 ----
    {
      f32x4 acc[2][4] = {};
#pragma unroll
      for (int kk = 0; kk < 128; kk += 32) {
        const int koff = kk + lhi * 8;
        bf16x8 a[2], b[4];
#pragma unroll
        for (int m = 0; m < 2; ++m)
          a[m] = *(const bf16x8*)&kb[wm * 32 + m * 16 + l15][koff];
#pragma unroll
        for (int n = 0; n < 4; ++n)
          b[n] = *(const bf16x8*)&MbfT[wn * 64 + n * 16 + l15][koff];
#pragma unroll
        for (int m = 0; m < 2; ++m)
#pragma unroll
          for (int n = 0; n < 4; ++n)
            acc[m][n] = __builtin_amdgcn_mfma_f32_16x16x32_bf16(a[m], b[n], acc[m][n], 0, 0, 0);
      }
#pragma unroll
      for (int m = 0; m < 2; ++m)
#pragma unroll
        for (int n = 0; n < 4; ++n) {
          int dv = wn * 64 + n * 16 + l15;
          int t0 = wm * 32 + m * 16 + lhi * 4;
          f32x4 v4 = *(const f32x4*)&vT[(size_t)(h * 128 + dv) * L_SEQ + l0 + t0];
#pragma unroll
          for (int j = 0; j < 4; ++j) {
            int t = t0 + j;
            float r = bts[t] * (v4[j] - expf(Gh[t]) * acc[m][n][j]);
            rTb[dv][t] = f2bf(r);
          }
        }
    }
    __syncthreads();

    // ---- delta = W @ r (64x128, K=64) -> DbT f32; decayed -> ddT bf16 ----
    {
      f32x4 acc[2][4] = {};
#pragma unroll
      for (int kk = 0; kk < 64; kk += 32) {
        const int koff = kk + lhi * 8;
        bf16x8 a[2], b[4];
#pragma unroll
        for (int m = 0; m < 2; ++m)
          a[m] = *(const bf16x8*)&Wbf[wm * 32 + m * 16 + l15][koff];
#pragma unroll
        for (int n = 0; n < 4; ++n)
          b[n] = *(const bf16x8*)&rTb[wn * 64 + n * 16 + l15][koff];
#pragma unroll
        for (int m = 0; m < 2; ++m)
#pragma unroll
          for (int n = 0; n < 4; ++n)
            acc[m][n] = __builtin_amdgcn_mfma_f32_16x16x32_bf16(a[m], b[n], acc[m][n], 0, 0, 0);
      }
      const float G63 = Gh[63];
#pragma unroll
      for (int m = 0; m < 2; ++m)
#pragma unroll
        for (int n = 0; n < 4; ++n) {
          int dv = wn * 64 + n * 16 + l15;
          int t0 = wm * 32 + m * 16 + lhi * 4;
          *(f32x4*)&DbT[(size_t)(h * 128 + dv) * L_SEQ + l0 + t0] = acc[m][n];
#pragma unroll
          for (int j = 0; j < 4; ++j) {
            int t = t0 + j;
            ddT[dv][t] = f2bf(acc[m][n][j] * expf(G63 - Gh[t]));
          }
        }
    }
    __syncthreads();

    // ---- M = E63*M + K^T @ ddT (128x128, K=64); refresh bf16 mirror ----
    {
      const float E63 = expf(Gh[63]);
      f32x4 acc[4][4];
#pragma unroll
      for (int m = 0; m < 4; ++m)
#pragma unroll
        for (int n = 0; n < 4; ++n)
#pragma unroll
          for (int j = 0; j < 4; ++j) acc[m][n][j] = E63 * Mreg[m][n][j];
#pragma unroll
      for (int kk = 0; kk < 64; kk += 32) {
        const int koff = kk + lhi * 8;
        bf16x8 a[4], b[4];
#pragma unroll
        for (int m = 0; m < 4; ++m)
          a[m] = *(const bf16x8*)&kbT[wm * 64 + m * 16 + l15][koff];
#pragma unroll
        for (int n = 0; n < 4; ++n)
          b[n] = *(const bf16x8*)&ddT[wn * 64 + n * 16 + l15][koff];
#pragma unroll
        for (int m = 0; m < 4; ++m)
#pragma unroll
          for (int n = 0; n < 4; ++n)
            acc[m][n] = __builtin_amdgcn_mfma_f32_16x16x32_bf16(a[m], b[n], acc[m][n], 0, 0, 0);
      }
#pragma unroll
      for (int m = 0; m < 4; ++m)
#pragma unroll
        for (int n = 0; n < 4; ++n) {
          Mreg[m][n] = acc[m][n];
          int dv = wn * 64 + n * 16 + l15;
          int dk0 = wm * 64 + m * 16 + lhi * 4;
#pragma unroll
          for (int j = 0; j < 4; ++j)
            MbfT[dv][dk0 + j] = f2bf(acc[m][n][j]);
        }
    }
    __syncthreads();
  }
}

// ---------------- MFMA output reconstruction + fused gated RMSNorm (R18-exact) ----
__global__ __launch_bounds__(256) void opass_kernel(const float* __restrict__ qn,
                                                    const float* __restrict__ kn,
                                                    const float* __restrict__ DbT,
                                                    const float* __restrict__ gT,
                                                    const float* __restrict__ Mb,
                                                    const float* __restrict__ qkvz,
                                                    const float* __restrict__ norm_w,
                                                    u16* __restrict__ gn) {
  __shared__ alignas(16) u16 qsb[64][136];
  __shared__ alignas(16) u16 bbuf[128][136];
  __shared__ alignas(16) u16 Asb[64][72];
  __shared__ float gsh[64], Gh[64];
  __shared__ float ssr[2][64];

  const int tid = threadIdx.x;
  const int lane = tid & 63, wave = tid >> 6;
  const int l15 = lane & 15, lhi = lane >> 4;
  const int h = blockIdx.x & 15, sc = blockIdx.x >> 4;
  const int l0 = sc * SCH;

  {
    int t = tid >> 2, c0 = (tid & 3) * 32;
    const float* qr = qn + ((size_t)h * L_SEQ + l0 + t) * 128 + c0;
    const float* kr = kn + ((size_t)h * L_SEQ + l0 + t) * 128 + c0;
#pragma unroll
    for (int j = 0; j < 8; ++j) {
      f32x4 vq = *(const f32x4*)&qr[j * 4];
      f32x4 vk = *(const f32x4*)&kr[j * 4];
      u16x4 oq = { f2bf(vq[0]), f2bf(vq[1]), f2bf(vq[2]), f2bf(vq[3]) };
      u16x4 ok = { f2bf(vk[0]), f2bf(vk[1]), f2bf(vk[2]), f2bf(vk[3]) };
      *(u16x4*)&qsb[t][c0 + j * 4] = oq;
      *(u16x4*)&bbuf[t][c0 + j * 4] = ok;
    }
  }
  if (tid < 64) gsh[tid] = gT[h * L_SEQ + l0 + tid];
  __syncthreads();
  if (tid < 64) {
    float a = 0.f;
    for (int u = 0; u <= tid; ++u) a += gsh[u];
    Gh[tid] = a;
  }
  __syncthreads();

  f32x4 acc1[2][2] = {};
  const int wm = wave >> 1, wn = wave & 1;
#pragma unroll
  for (int kk = 0; kk < 128; kk += 32) {
    const int koff = kk + lhi * 8;
    bf16x8 a[2], b[2];
#pragma unroll
    for (int m = 0; m < 2; ++m)
      a[m] = *(const bf16x8*)&qsb[wm * 32 + m * 16 + l15][koff];
#pragma unroll
    for (int n = 0; n < 2; ++n)
      b[n] = *(const bf16x8*)&bbuf[wn * 32 + n * 16 + l15][koff];
#pragma unroll
    for (int m = 0; m < 2; ++m)
#pragma unroll
      for (int n = 0; n < 2; ++n)
        acc1[m][n] = __builtin_amdgcn_mfma_f32_16x16x32_bf16(a[m], b[n], acc1[m][n], 0, 0, 0);
  }
#pragma unroll
  for (int m = 0; m < 2; ++m)
#pragma unroll
    for (int n = 0; n < 2; ++n)
#pragma unroll
      for (int j = 0; j < 4; ++j) {
        int t = wm * 32 + m * 16 + lhi * 4 + j;
        int s = wn * 32 + n * 16 + l15;
        float a = (s <= t) ? acc1[m][n][j] * expf(Gh[t] - Gh[s]) : 0.f;
        Asb[t][s] = f2bf(a);
      }
  __syncthreads();

  {
    int dv = tid >> 1, c0 = (tid & 1) * 64;
    const float* mr = Mb + (((size_t)sc * 16 + h) * 128 + dv) * 128 + c0;
#pragma unroll
    for (int j = 0; j < 16; ++j) {
      f32x4 v = *(const f32x4*)&mr[j * 4];
      u16x4 o = { f2bf(v[0]), f2bf(v[1]), f2bf(v[2]), f2bf(v[3]) };
      *(u16x4*)&bbuf[dv][c0 + j * 4] = o;
    }
  }
  __syncthreads();

  f32x4 acc[2][4] = {};
#pragma unroll
  for (int kk = 0; kk < 128; kk += 32) {
    const int koff = kk + lhi * 8;
    bf16x8 a[2], b[4];
#pragma unroll
    for (int m = 0; m < 2; ++m)
      a[m] = *(const bf16x8*)&qsb[wm * 32 + m * 16 + l15][koff];
#pragma unroll
    for (int n = 0; n < 4; ++n)
      b[n] = *(const bf16x8*)&bbuf[wn * 64 + n * 16 + l15][koff];
#pragma unroll
    for (int m = 0; m < 2; ++m)
#pragma unroll
      for (int n = 0; n < 4; ++n)
        acc[m][n] = __builtin_amdgcn_mfma_f32_16x16x32_bf16(a[m], b[n], acc[m][n], 0, 0, 0);
  }
#pragma unroll
  for (int m = 0; m < 2; ++m) {
#pragma unroll
    for (int j = 0; j < 4; ++j) {
      int t = wm * 32 + m * 16 + lhi * 4 + j;
      float sc1 = expf(Gh[t]);
#pragma unroll
      for (int n = 0; n < 4; ++n) acc[m][n][j] *= sc1;
    }
  }
  __syncthreads();

  {
    int dv = tid >> 1, c0 = (tid & 1) * 32;
    const float* dr = DbT + (size_t)(h * 128 + dv) * L_SEQ + l0 + c0;
#pragma unroll
    for (int j = 0; j < 8; ++j) {
      f32x4 v = *(const f32x4*)&dr[j * 4];
      u16x4 o = { f2bf(v[0]), f2bf(v[1]), f2bf(v[2]), f2bf(v[3]) };
      *(u16x4*)&bbuf[dv][c0 + j * 4] = o;
    }
  }
  __syncthreads();

#pragma unroll
  for (int kk = 0; kk < 64; kk += 32) {
    const int koff = kk + lhi * 8;
    bf16x8 a[2], b[4];
#pragma unroll
    for (int m = 0; m < 2; ++m)
      a[m] = *(const bf16x8*)&Asb[wm * 32 + m * 16 + l15][koff];
#pragma unroll
    for (int n = 0; n < 4; ++n)
      b[n] = *(const bf16x8*)&bbuf[wn * 64 + n * 16 + l15][koff];
#pragma unroll
    for (int m = 0; m < 2; ++m)
#pragma unroll
      for (int n = 0; n < 4; ++n)
        acc[m][n] = __builtin_amdgcn_mfma_f32_16x16x32_bf16(a[m], b[n], acc[m][n], 0, 0, 0);
  }

  float pr[2][4];
#pragma unroll
  for (int m = 0; m < 2; ++m)
#pragma unroll
    for (int j = 0; j < 4; ++j) {
      float p = 0.f;
#pragma unroll
      for (int n = 0; n < 4; ++n) p = fmaf(acc[m][n][j], acc[m][n][j], p);
      pr[m][j] = red16(p);
    }
  if (l15 == 0) {
#pragma unroll
    for (int m = 0; m < 2; ++m)
#pragma unroll
      for (int j = 0; j < 4; ++j)
        ssr[wn][wm * 32 + m * 16 + lhi * 4 + j] = pr[m][j];
  }
  __syncthreads();
#pragma unroll
  for (int m = 0; m < 2; ++m)
#pragma unroll
    for (int j = 0; j < 4; ++j) {
      int t = wm * 32 + m * 16 + lhi * 4 + j;
      float ss = ssr[0][t] + ssr[1][t];
      float r = 1.f / sqrtf(ss * (1.f / 128.f) + 1e-6f);
      const float* zp = qkvz + (size_t)(l0 + t) * QZD + CONVD + h * 128;
      u16* dst = gn + (size_t)(l0 + t) * VALD + h * 128;
#pragma unroll
      for (int n = 0; n < 4; ++n) {
        int dv = wn * 64 + n * 16 + l15;
        float z = zp[dv];
        float sil = z / (1.f + expf(-z));
        dst[dv] = f2bf(acc[m][n][j] * r * norm_w[dv] * sil);
      }
    }
}

extern "C" void kernel_launch(void* const* d_in, const int* in_sizes, int n_in,
                              void* d_out, int out_size, void* d_ws, size_t ws_size,
                              hipStream_t stream) {
  const float* x      = (const float*)d_in[0];
  const float* Wqkv   = (const float*)d_in[1];
  const float* Wz     = (const float*)d_in[2];
  const float* Wb     = (const float*)d_in[3];
  const float* Wa     = (const float*)d_in[4];
  const float* conv_w = (const float*)d_in[5];
  const float* A_log  = (const float*)d_in[6];
  const float* dt_bias= (const float*)d_in[7];
  const float* norm_w = (const float*)d_in[8];
  const float* Wout   = (const float*)d_in[9];
  float* out = (float*)d_out;

  char* ws = (char*)d_ws;
  size_t off = 0;
  auto alloc = [&](size_t bytes) {
    void* p = ws + off;
    off = (off + bytes + 255) & ~(size_t)255;
    return p;
  };
  u16* xb     = (u16*)alloc((size_t)L_SEQ * IDIM_ * 2);
  u16* WcatT  = (u16*)alloc((size_t)QZD * IDIM_ * 2);
  u16* WoutT  = (u16*)alloc((size_t)IDIM_ * VALD * 2);
  float* qkvz = (float*)alloc((size_t)L_SEQ * QZD * 4);
  float* qn   = (float*)alloc((size_t)H_ * L_SEQ * 128 * 4);
  float* kn   = (float*)alloc((size_t)H_ * L_SEQ * 128 * 4);
  float* vT   = (float*)alloc((size_t)H_ * 128 * L_SEQ * 4);
  float* btT  = (float*)alloc((size_t)L_SEQ * H_ * 4);
  float* gTb  = (float*)alloc((size_t)L_SEQ * H_ * 4);
  float* Wgb  = (float*)alloc((size_t)NSC * H_ * 64 * 64 * 4);    // 4MB
  float* Mb   = (float*)alloc((size_t)NSC * H_ * 128 * 128 * 4);  // 16MB
  float* DbT  = (float*)alloc((size_t)H_ * 128 * L_SEQ * 4);      // 8MB
  u16* gn     = (u16*)alloc((size_t)L_SEQ * VALD * 2);

  // merged casts/transposes + gate-weight rows + zero pad (1 launch)
  prepcast_kernel<<<22616, 256, 0, stream>>>(x, Wqkv, Wz, Wb, Wa, Wout, xb, WcatT, WoutT);

  // combined projection [qkv | z | gates]
  gemm_bt_kernel<<<dim3(QZD / 128, L_SEQ / 128), 256, 0, stream>>>(xb, WcatT, qkvz, L_SEQ, QZD, IDIM_);

  // gates
  gatelite_kernel<<<64, 256, 0, stream>>>(qkvz, A_log, dt_bias, btT, gTb);

  // merged prep2
  prep2_kernel<<<6144, 256, 0, stream>>>(qkvz, conv_w, qn, kn, vT);

  // chunked-WY scan: W precompute (parallel) + MFMA chunk recurrence (16 blocks)
  winv_kernel<<<NSC * H_, 256, 0, stream>>>(kn, gTb, btT, Wgb);
  wyscan_kernel<<<H_, 256, 0, stream>>>(kn, vT, gTb, btT, Wgb, Mb, DbT);

  // MFMA output reconstruction + fused gated RMSNorm
  opass_kernel<<<NSC * H_, 256, 0, stream>>>(qn, kn, DbT, gTb, Mb, qkvz, norm_w, gn);

  // final projection
  gemm_bt64_kernel<<<256, 256, 0, stream>>>(gn, WoutT, out, L_SEQ, IDIM_, VALD, 1);
}

// Round 21
// 321.907 us; speedup vs baseline: 1.1282x; 1.1270x over previous
//
#include <hip/hip_runtime.h>

typedef short bf16x8 __attribute__((ext_vector_type(8)));
typedef float f32x4 __attribute__((ext_vector_type(4)));
typedef float f32x2 __attribute__((ext_vector_type(2)));
typedef unsigned short u16;
typedef u16 u16x4 __attribute__((ext_vector_type(4)));

#define L_SEQ 1024
#define IDIM_ 2048
#define H_ 16
#define DK_ 128
#define DV_ 128
#define KEYD 2048
#define VALD 2048
#define CONVD 6144
#define QZD 8320          // qkv(6144) | z(2048) | b(16) | a(16) | pad(96)
#define GCOL 8192         // gate column base
#define CH 16
#define NCH (L_SEQ / CH)
#define SCH 64
#define NSC (L_SEQ / SCH)

__device__ __forceinline__ u16 f2bf(float f) {
  union { float f; unsigned u; } v; v.f = f;
  unsigned r = v.u + 0x7FFF + ((v.u >> 16) & 1);  // RNE
  return (u16)(r >> 16);
}

// 16-lane allreduce, all-DPP (VALU only). Verified R3-R20.
__device__ __forceinline__ float red16(float x) {
  union U { float f; int i; } a, t;
  a.f = x;
  t.i = __builtin_amdgcn_update_dpp(0, a.i, 0xB1, 0xF, 0xF, true); a.f += t.f;
  t.i = __builtin_amdgcn_update_dpp(0, a.i, 0x4E, 0xF, 0xF, true); a.f += t.f;
  t.i = __builtin_amdgcn_update_dpp(0, a.i, 0x141, 0xF, 0xF, true); a.f += t.f;
  t.i = __builtin_amdgcn_update_dpp(0, a.i, 0x140, 0xF, 0xF, true); a.f += t.f;
  return a.f;
}

__device__ __forceinline__ void gl_lds16(const float* g, float* l) {
  __builtin_amdgcn_global_load_lds(
      (const __attribute__((address_space(1))) void*)g,
      (__attribute__((address_space(3))) void*)l, 16, 0, 0);
}
__device__ __forceinline__ void gl_lds4(const float* g, float* l) {
  __builtin_amdgcn_global_load_lds(
      (const __attribute__((address_space(1))) void*)g,
      (__attribute__((address_space(3))) void*)l, 4, 0, 0);
}

// ---- merged cast/transpose prep ----
// [0,2048) castx | [2048,14336) Wqkv | [14336,18432) Wz | [18432,22528) Wout
// [22528,22592) Wb/Wa gate rows | [22592,22616) zero pad rows 8224..8319
__global__ __launch_bounds__(256) void prepcast_kernel(const float* __restrict__ x,
                                                       const float* __restrict__ Wqkv,
                                                       const float* __restrict__ Wz,
                                                       const float* __restrict__ Wb,
                                                       const float* __restrict__ Wa,
                                                       const float* __restrict__ Wout,
                                                       u16* __restrict__ xb,
                                                       u16* __restrict__ WcatT,
                                                       u16* __restrict__ WoutT) {
  __shared__ float tile[32][33];
  const int bid = blockIdx.x;
  if (bid < 2048) {
    int i = (bid * 256 + threadIdx.x) * 4;
    f32x4 v = *(const f32x4*)&x[i];
    u16x4 o = { f2bf(v[0]), f2bf(v[1]), f2bf(v[2]), f2bf(v[3]) };
    *(u16x4*)&xb[i] = o;
    return;
  }
  if (bid >= 22592) {   // zero pad rows [8224,8320) of WcatT
    size_t off = (size_t)8224 * IDIM_ + (size_t)(bid - 22592) * 8192 + threadIdx.x * 32;
    u16x4 z = {0, 0, 0, 0};
#pragma unroll
    for (int j = 0; j < 8; ++j) *(u16x4*)&WcatT[off + j * 4] = z;
    return;
  }
  if (bid >= 22528) {   // Wb -> rows 8192..8207, Wa -> rows 8208..8223
    int by = bid - 22528;
    int r = threadIdx.x >> 3, c8 = threadIdx.x & 7;
    int row = by * 32 + r;
#pragma unroll
    for (int cc = 0; cc < 2; ++cc) {
      int c = cc * 8 + c8;
      WcatT[(size_t)(GCOL + c) * IDIM_ + row]      = f2bf(Wb[(size_t)row * 16 + c]);
      WcatT[(size_t)(GCOL + 16 + c) * IDIM_ + row] = f2bf(Wa[(size_t)row * 16 + c]);
    }
    return;
  }
  const float* W; u16* WT; int R, C, bx, by;
  if (bid < 14336) {
    int t = bid - 2048;  bx = t % 192; by = t / 192;
    W = Wqkv; WT = WcatT; R = IDIM_; C = CONVD;
  } else if (bid < 18432) {
    int t = bid - 14336; bx = t & 63; by = t >> 6;
    W = Wz; WT = WcatT + (size_t)CONVD * IDIM_; R = IDIM_; C = VALD;
  } else {
    int t = bid - 18432; bx = t & 63; by = t >> 6;
    W = Wout; WT = WoutT; R = VALD; C = IDIM_;
  }
  int c0 = bx * 32, r0 = by * 32;
  int tx = threadIdx.x & 31, ty = threadIdx.x >> 5;
#pragma unroll
  for (int j = 0; j < 4; ++j)
    tile[ty + j * 8][tx] = W[(size_t)(r0 + ty + j * 8) * C + c0 + tx];
  __syncthreads();
#pragma unroll
  for (int j = 0; j < 4; ++j)
    WT[(size_t)(c0 + ty + j * 8) * R + r0 + tx] = f2bf(tile[tx][ty + j * 8]);
}

// ---------------- NT GEMM (2D grid) ----------------
__global__ __launch_bounds__(256) void gemm_bt_kernel(const u16* __restrict__ A,
                                                      const u16* __restrict__ B,
                                                      float* __restrict__ C,
                                                      int M, int N, int K) {
  __shared__ short As[128 * 72];
  __shared__ short Bs[128 * 72];
  const int tid = threadIdx.x;
  const int lane = tid & 63, wave = tid >> 6;
  const int wm = wave >> 1, wn = wave & 1;
  const int m0 = blockIdx.y * 128, n0 = blockIdx.x * 128;
  const int l15 = lane & 15, lhi = lane >> 4;

  f32x4 acc[4][4] = {};

  for (int k0 = 0; k0 < K; k0 += 64) {
    __syncthreads();
#pragma unroll
    for (int i = 0; i < 4; ++i) {
      int chunk = tid + i * 256;
      int row = chunk >> 3;
      int kc = (chunk & 7) * 8;
      *(bf16x8*)&As[row * 72 + kc] =
          *(const bf16x8*)&A[(size_t)(m0 + row) * K + k0 + kc];
      *(bf16x8*)&Bs[row * 72 + kc] =
          *(const bf16x8*)&B[(size_t)(n0 + row) * K + k0 + kc];
    }
    __syncthreads();
#pragma unroll
    for (int kk = 0; kk < 64; kk += 32) {
      const int koff = kk + lhi * 8;
      bf16x8 a[4], b[4];
#pragma unroll
      for (int m = 0; m < 4; ++m)
        a[m] = *(const bf16x8*)&As[(wm * 64 + m * 16 + l15) * 72 + koff];
#pragma unroll
      for (int n = 0; n < 4; ++n)
        b[n] = *(const bf16x8*)&Bs[(wn * 64 + n * 16 + l15) * 72 + koff];
#pragma unroll
      for (int m = 0; m < 4; ++m)
#pragma unroll
        for (int n = 0; n < 4; ++n)
          acc[m][n] = __builtin_amdgcn_mfma_f32_16x16x32_bf16(a[m], b[n], acc[m][n], 0, 0, 0);
    }
  }
#pragma unroll
  for (int m = 0; m < 4; ++m)
#pragma unroll
    for (int n = 0; n < 4; ++n)
#pragma unroll
      for (int j = 0; j < 4; ++j) {
        int row = m0 + wm * 64 + m * 16 + lhi * 4 + j;
        int col = n0 + wn * 64 + n * 16 + l15;
        C[(size_t)row * N + col] = acc[m][n][j];
      }
}

// ---------------- NT GEMM BM=64, XCD-chunked 1D grid ----------------
__global__ __launch_bounds__(256) void gemm_bt64_kernel(const u16* __restrict__ A,
                                                        const u16* __restrict__ B,
                                                        float* __restrict__ C,
                                                        int M, int N, int K, int cxl) {
  __shared__ short As[64 * 72];
  __shared__ short Bs[128 * 72];
  const int tid = threadIdx.x;
  const int lane = tid & 63, wave = tid >> 6;
  const int wm = wave >> 1, wn = wave & 1;
  const int bid = blockIdx.x;
  const int xcd = bid & 7, bi = bid >> 3;
  const int bx = (xcd << cxl) + (bi & ((1 << cxl) - 1));
  const int by = bi >> cxl;
  const int m0 = by * 64, n0 = bx * 128;
  const int l15 = lane & 15, lhi = lane >> 4;

  f32x4 acc[2][4] = {};

  for (int k0 = 0; k0 < K; k0 += 64) {
    __syncthreads();
#pragma unroll
    for (int i = 0; i < 2; ++i) {
      int chunk = tid + i * 256;
      int row = chunk >> 3;
      int kc = (chunk & 7) * 8;
      *(bf16x8*)&As[row * 72 + kc] =
          *(const bf16x8*)&A[(size_t)(m0 + row) * K + k0 + kc];
    }
#pragma unroll
    for (int i = 0; i < 4; ++i) {
      int chunk = tid + i * 256;
      int row = chunk >> 3;
      int kc = (chunk & 7) * 8;
      *(bf16x8*)&Bs[row * 72 + kc] =
          *(const bf16x8*)&B[(size_t)(n0 + row) * K + k0 + kc];
    }
    __syncthreads();
#pragma unroll
    for (int kk = 0; kk < 64; kk += 32) {
      const int koff = kk + lhi * 8;
      bf16x8 a[2], b[4];
#pragma unroll
      for (int m = 0; m < 2; ++m)
        a[m] = *(const bf16x8*)&As[(wm * 32 + m * 16 + l15) * 72 + koff];
#pragma unroll
      for (int n = 0; n < 4; ++n)
        b[n] = *(const bf16x8*)&Bs[(wn * 64 + n * 16 + l15) * 72 + koff];
#pragma unroll
      for (int m = 0; m < 2; ++m)
#pragma unroll
        for (int n = 0; n < 4; ++n)
          acc[m][n] = __builtin_amdgcn_mfma_f32_16x16x32_bf16(a[m], b[n], acc[m][n], 0, 0, 0);
    }
  }
#pragma unroll
  for (int m = 0; m < 2; ++m)
#pragma unroll
    for (int n = 0; n < 4; ++n)
#pragma unroll
      for (int j = 0; j < 4; ++j) {
        int row = m0 + wm * 32 + m * 16 + lhi * 4 + j;
        int col = n0 + wn * 64 + n * 16 + l15;
        C[(size_t)row * N + col] = acc[m][n][j];
      }
}

// -------- gatelite: gates from qkvz cols 8192..8223 --------
__global__ __launch_bounds__(256) void gatelite_kernel(const float* __restrict__ qkvz,
                                                       const float* __restrict__ A_log,
                                                       const float* __restrict__ dt_bias,
                                                       float* __restrict__ btT,
                                                       float* __restrict__ egT,
                                                       float* __restrict__ gT) {
  int gid = blockIdx.x * 256 + threadIdx.x;  // 16384: l*16+h
  int l = gid >> 4, h = gid & 15;
  const float* row = qkvz + (size_t)l * QZD + GCOL;
  float b = row[h], a = row[16 + h];
  btT[h * L_SEQ + l] = 1.f / (1.f + expf(-b));
  float dtv = a + dt_bias[h];
  dtv = (dtv > 20.f) ? dtv : log1pf(expf(dtv));
  float g = -expf(A_log[h]) * dtv;
  egT[h * L_SEQ + l] = expf(g);
  gT[h * L_SEQ + l] = g;
}

// ---- merged prep2: conv+SiLU+l2norm q/k repack; v transpose ----
__global__ __launch_bounds__(256) void prep2_kernel(const float* __restrict__ qkvz,
                                                    const float* __restrict__ cw,
                                                    float* __restrict__ qn,
                                                    float* __restrict__ kn,
                                                    float* __restrict__ vT) {
  __shared__ float tile[32][33];
  const int bid = blockIdx.x;
  if (bid < 4096) {
    int wid = bid * 4 + (threadIdx.x >> 6);
    int lane = threadIdx.x & 63;
    int l = wid >> 4, h = wid & 15;
    const int cq = h * 128 + lane * 2;
    const int ck = KEYD + cq;
    const float* row0 = qkvz + (size_t)l * QZD;
    f32x4 wq0 = *(const f32x4*)&cw[cq * 4];
    f32x4 wq1 = *(const f32x4*)&cw[(cq + 1) * 4];
    f32x4 wk0 = *(const f32x4*)&cw[ck * 4];
    f32x4 wk1 = *(const f32x4*)&cw[(ck + 1) * 4];
    f32x2 xq = *(const f32x2*)&row0[cq];
    f32x2 xk = *(const f32x2*)&row0[ck];
    float q0 = xq[0] * wq0[3], q1 = xq[1] * wq1[3];
    float k0 = xk[0] * wk0[3], k1 = xk[1] * wk1[3];
    if (l >= 1) {
      f32x2 aq = *(const f32x2*)&row0[cq - QZD];
      f32x2 ak = *(const f32x2*)&row0[ck - QZD];
      q0 += aq[0] * wq0[2]; q1 += aq[1] * wq1[2];
      k0 += ak[0] * wk0[2]; k1 += ak[1] * wk1[2];
    }
    if (l >= 2) {
      f32x2 aq = *(const f32x2*)&row0[cq - 2 * QZD];
      f32x2 ak = *(const f32x2*)&row0[ck - 2 * QZD];
      q0 += aq[0] * wq0[1]; q1 += aq[1] * wq1[1];
      k0 += ak[0] * wk0[1]; k1 += ak[1] * wk1[1];
    }
    if (l >= 3) {
      f32x2 aq = *(const f32x2*)&row0[cq - 3 * QZD];
      f32x2 ak = *(const f32x2*)&row0[ck - 3 * QZD];
      q0 += aq[0] * wq0[0]; q1 += aq[1] * wq1[0];
      k0 += ak[0] * wk0[0]; k1 += ak[1] * wk1[0];
    }
    f32x2 qv = { q0 / (1.f + expf(-q0)), q1 / (1.f + expf(-q1)) };
    f32x2 kv = { k0 / (1.f + expf(-k0)), k1 / (1.f + expf(-k1)) };

    float ssq = qv[0] * qv[0] + qv[1] * qv[1];
    float ssk = kv[0] * kv[0] + kv[1] * kv[1];
#pragma unroll
    for (int s = 1; s < 64; s <<= 1) {
      ssq += __shfl_xor(ssq, s);
      ssk += __shfl_xor(ssk, s);
    }
    float scq = 0.08838834764831845f / sqrtf(ssq + 1e-6f);
    float sck = 1.f / sqrtf(ssk + 1e-6f);
    qv[0] *= scq; qv[1] *= scq;
    kv[0] *= sck; kv[1] *= sck;
    size_t base = ((size_t)h * L_SEQ + l) * 128 + lane * 2;
    *(f32x2*)&qn[base] = qv;
    *(f32x2*)&kn[base] = kv;
    return;
  }
  int t = bid - 4096;
  int c0 = (t & 63) * 32, l0 = (t >> 6) * 32;
  int tx = threadIdx.x & 31, ty = threadIdx.x >> 5;
  const int c = 2 * KEYD + c0 + tx;
  f32x4 w = *(const f32x4*)&cw[c * 4];
#pragma unroll
  for (int j = 0; j < 4; ++j) {
    int l = l0 + ty + j * 8;
    const float* p = qkvz + (size_t)l * QZD + c;
    float s = p[0] * w[3];
    if (l >= 1) s += p[-QZD] * w[2];
    if (l >= 2) s += p[-2 * QZD] * w[1];
    if (l >= 3) s += p[-3 * QZD] * w[0];
    tile[ty + j * 8][tx] = s / (1.f + expf(-s));
  }
  __syncthreads();
#pragma unroll
  for (int j = 0; j < 4; ++j)
    vT[(size_t)(c0 + ty + j * 8) * L_SEQ + l0 + tx] = tile[tx][ty + j * 8];
}

// ---------------- scan v12: output-deferred (R16-R18 passing, 116us) ----------
__global__ __launch_bounds__(256) void scan_kernel(const float* __restrict__ kn,
                                                   const float* __restrict__ vT,
                                                   const float* __restrict__ egT,
                                                   const float* __restrict__ btT,
                                                   float* __restrict__ Mb,
                                                   float* __restrict__ DbT) {
  __shared__ alignas(16) float ks[2][CH][128];
  __shared__ alignas(16) float vs[2][16][CH];
  __shared__ alignas(16) float ebc[2][2][CH];

  const int tid = threadIdx.x;
  const int wave = tid >> 6, lane = tid & 63;
  const int dk_sub = lane & 15;
  const int head = blockIdx.x & 15;
  const int dv0 = (blockIdx.x >> 4) * 16;
  const int col_local = tid >> 4;
  const int dv = dv0 + col_local;

  const float* kh = kn + (size_t)head * L_SEQ * 128;

  auto stage = [&](int chunk, int buf) {
    const int l0 = chunk * CH;
    const float* kg = kh + (size_t)l0 * 128;
#pragma unroll
    for (int i = 0; i < 2; ++i) {
      int seg = i * 4 + wave;
      int off = seg * 256 + lane * 4;
      gl_lds16(kg + off, &ks[buf][0][0] + seg * 256);
    }
    {
      int idx = wave * 64 + lane;
      gl_lds4(vT + (size_t)(head * 128 + dv0 + (idx >> 4)) * L_SEQ + l0 + (idx & 15),
              &vs[buf][0][0] + wave * 64);
    }
    if (wave == 0 && lane < 32) {
      const float* src = (lane < 16) ? (egT + head * L_SEQ + l0 + lane)
                                     : (btT + head * L_SEQ + l0 + (lane - 16));
      gl_lds4(src, &ebc[buf][0][0]);
    }
  };

  stage(0, 0);
  __syncthreads();

  f32x4 Mlo = {0.f, 0.f, 0.f, 0.f}, Mhi = {0.f, 0.f, 0.f, 0.f};
  const int dkb = dk_sub * 8;
  float* dcol = DbT + (size_t)(head * 128 + dv) * L_SEQ;

#pragma unroll 1
  for (int c = 0; c < NCH; ++c) {
    const int buf = c & 1;
    if (c + 1 < NCH) stage(c + 1, buf ^ 1);

    if ((c & 3) == 0) {
      int sc = c >> 2;
      float* mrow = Mb + (((size_t)sc * 16 + head) * 128 + dv) * 128 + dkb;
      *(f32x4*)mrow = Mlo;
      *(f32x4*)(mrow + 4) = Mhi;
    }

    f32x4 ev[4], bv[4], vv[4];
#pragma unroll
    for (int i = 0; i < 4; ++i) {
      ev[i] = *(const f32x4*)&ebc[buf][0][i * 4];
      bv[i] = *(const f32x4*)&ebc[buf][1][i * 4];
      vv[i] = *(const f32x4*)&vs[buf][col_local][i * 4];
    }
    f32x4 kr[4][2];
#pragma unroll
    for (int i = 0; i < 3; ++i) {
      kr[i][0] = *(const f32x4*)&ks[buf][i][dkb];
      kr[i][1] = *(const f32x4*)&ks[buf][i][dkb + 4];
    }

#pragma unroll
    for (int s = 0; s < CH; ++s) {
      if (s + 3 < CH) {
        kr[(s + 3) & 3][0] = *(const f32x4*)&ks[buf][s + 3][dkb];
        kr[(s + 3) & 3][1] = *(const f32x4*)&ks[buf][s + 3][dkb + 4];
      }
      const f32x4 k0 = kr[s & 3][0], k1 = kr[s & 3][1];
      const float e = ev[s >> 2][s & 3], b = bv[s >> 2][s & 3];
      const float v = vv[s >> 2][s & 3];

      float skm0 = k0[0] * Mlo[0], skm1 = k0[1] * Mlo[1];
      skm0 = fmaf(k0[2], Mlo[2], skm0); skm1 = fmaf(k0[3], Mlo[3], skm1);
      skm0 = fmaf(k1[0], Mhi[0], skm0); skm1 = fmaf(k1[1], Mhi[1], skm1);
      skm0 = fmaf(k1[2], Mhi[2], skm0); skm1 = fmaf(k1[3], Mhi[3], skm1);
      f32x4 emlo, emhi;
#pragma unroll
      for (int i = 0; i < 4; ++i) { emlo[i] = e * Mlo[i]; emhi[i] = e * Mhi[i]; }
      float skm = red16(skm0 + skm1);
      float dl = (v - e * skm) * b;
      if (dk_sub == 0) dcol[c * CH + s] = dl;
#pragma unroll
      for (int i = 0; i < 4; ++i) {
        Mlo[i] = fmaf(k0[i], dl, emlo[i]);
        Mhi[i] = fmaf(k1[i], dl, emhi[i]);
      }
    }
    __syncthreads();
  }
}

// ---------------- MFMA output reconstruction + fused gated RMSNorm ----------
__global__ __launch_bounds__(256) void opass_kernel(const float* __restrict__ qn,
                                                    const float* __restrict__ kn,
                                                    const float* __restrict__ DbT,
                                                    const float* __restrict__ gT,
                                                    const float* __restrict__ Mb,
                                                    const float* __restrict__ qkvz,
                                                    const float* __restrict__ norm_w,
                                                    u16* __restrict__ gn) {
  __shared__ alignas(16) u16 qsb[64][136];
  __shared__ alignas(16) u16 bbuf[128][136];
  __shared__ alignas(16) u16 Asb[64][72];
  __shared__ float gsh[64], Gh[64];
  __shared__ float ssr[2][64];

  const int tid = threadIdx.x;
  const int lane = tid & 63, wave = tid >> 6;
  const int l15 = lane & 15, lhi = lane >> 4;
  const int h = blockIdx.x & 15, sc = blockIdx.x >> 4;
  const int l0 = sc * SCH;

  {
    int t = tid >> 2, c0 = (tid & 3) * 32;
    const float* qr = qn + ((size_t)h * L_SEQ + l0 + t) * 128 + c0;
    const float* kr = kn + ((size_t)h * L_SEQ + l0 + t) * 128 + c0;
#pragma unroll
    for (int j = 0; j < 8; ++j) {
      f32x4 vq = *(const f32x4*)&qr[j * 4];
      f32x4 vk = *(const f32x4*)&kr[j * 4];
      u16x4 oq = { f2bf(vq[0]), f2bf(vq[1]), f2bf(vq[2]), f2bf(vq[3]) };
      u16x4 ok = { f2bf(vk[0]), f2bf(vk[1]), f2bf(vk[2]), f2bf(vk[3]) };
      *(u16x4*)&qsb[t][c0 + j * 4] = oq;
      *(u16x4*)&bbuf[t][c0 + j * 4] = ok;
    }
  }
  if (tid < 64) gsh[tid] = gT[h * L_SEQ + l0 + tid];
  __syncthreads();
  if (tid < 64) {
    float a = 0.f;
    for (int u = 0; u <= tid; ++u) a += gsh[u];
    Gh[tid] = a;
  }
  __syncthreads();

  f32x4 acc1[2][2] = {};
  const int wm = wave >> 1, wn = wave & 1;
#pragma unroll
  for (int kk = 0; kk < 128; kk += 32) {
    const int koff = kk + lhi * 8;
    bf16x8 a[2], b[2];
#pragma unroll
    for (int m = 0; m < 2; ++m)
      a[m] = *(const bf16x8*)&qsb[wm * 32 + m * 16 + l15][koff];
#pragma unroll
    for (int n = 0; n < 2; ++n)
      b[n] = *(const bf16x8*)&bbuf[wn * 32 + n * 16 + l15][koff];
#pragma unroll
    for (int m = 0; m < 2; ++m)
#pragma unroll
      for (int n = 0; n < 2; ++n)
        acc1[m][n] = __builtin_amdgcn_mfma_f32_16x16x32_bf16(a[m], b[n], acc1[m][n], 0, 0, 0);
  }
#pragma unroll
  for (int m = 0; m < 2; ++m)
#pragma unroll
    for (int n = 0; n < 2; ++n)
#pragma unroll
      for (int j = 0; j < 4; ++j) {
        int t = wm * 32 + m * 16 + lhi * 4 + j;
        int s = wn * 32 + n * 16 + l15;
        float a = (s <= t) ? acc1[m][n][j] * expf(Gh[t] - Gh[s]) : 0.f;
        Asb[t][s] = f2bf(a);
      }
  __syncthreads();

  {
    int dv = tid >> 1, c0 = (tid & 1) * 64;
    const float* mr = Mb + (((size_t)sc * 16 + h) * 128 + dv) * 128 + c0;
#pragma unroll
    for (int j = 0; j < 16; ++j) {
      f32x4 v = *(const f32x4*)&mr[j * 4];
      u16x4 o = { f2bf(v[0]), f2bf(v[1]), f2bf(v[2]), f2bf(v[3]) };
      *(u16x4*)&bbuf[dv][c0 + j * 4] = o;
    }
  }
  __syncthreads();

  f32x4 acc[2][4] = {};
#pragma unroll
  for (int kk = 0; kk < 128; kk += 32) {
    const int koff = kk + lhi * 8;
    bf16x8 a[2], b[4];
#pragma unroll
    for (int m = 0; m < 2; ++m)
      a[m] = *(const bf16x8*)&qsb[wm * 32 + m * 16 + l15][koff];
#pragma unroll
    for (int n = 0; n < 4; ++n)
      b[n] = *(const bf16x8*)&bbuf[wn * 64 + n * 16 + l15][koff];
#pragma unroll
    for (int m = 0; m < 2; ++m)
#pragma unroll
      for (int n = 0; n < 4; ++n)
        acc[m][n] = __builtin_amdgcn_mfma_f32_16x16x32_bf16(a[m], b[n], acc[m][n], 0, 0, 0);
  }
#pragma unroll
  for (int m = 0; m < 2; ++m) {
#pragma unroll
    for (int j = 0; j < 4; ++j) {
      int t = wm * 32 + m * 16 + lhi * 4 + j;
      float sc1 = expf(Gh[t]);
#pragma unroll
      for (int n = 0; n < 4; ++n) acc[m][n][j] *= sc1;
    }
  }
  __syncthreads();

  {
    int dv = tid >> 1, c0 = (tid & 1) * 32;
    const float* dr = DbT + (size_t)(h * 128 + dv) * L_SEQ + l0 + c0;
#pragma unroll
    for (int j = 0; j < 8; ++j) {
      f32x4 v = *(const f32x4*)&dr[j * 4];
      u16x4 o = { f2bf(v[0]), f2bf(v[1]), f2bf(v[2]), f2bf(v[3]) };
      *(u16x4*)&bbuf[dv][c0 + j * 4] = o;
    }
  }
  __syncthreads();

#pragma unroll
  for (int kk = 0; kk < 64; kk += 32) {
    const int koff = kk + lhi * 8;
    bf16x8 a[2], b[4];
#pragma unroll
    for (int m = 0; m < 2; ++m)
      a[m] = *(const bf16x8*)&Asb[wm * 32 + m * 16 + l15][koff];
#pragma unroll
    for (int n = 0; n < 4; ++n)
      b[n] = *(const bf16x8*)&bbuf[wn * 64 + n * 16 + l15][koff];
#pragma unroll
    for (int m = 0; m < 2; ++m)
#pragma unroll
      for (int n = 0; n < 4; ++n)
        acc[m][n] = __builtin_amdgcn_mfma_f32_16x16x32_bf16(a[m], b[n], acc[m][n], 0, 0, 0);
  }

  float pr[2][4];
#pragma unroll
  for (int m = 0; m < 2; ++m)
#pragma unroll
    for (int j = 0; j < 4; ++j) {
      float p = 0.f;
#pragma unroll
      for (int n = 0; n < 4; ++n) p = fmaf(acc[m][n][j], acc[m][n][j], p);
      pr[m][j] = red16(p);
    }
  if (l15 == 0) {
#pragma unroll
    for (int m = 0; m < 2; ++m)
#pragma unroll
      for (int j = 0; j < 4; ++j)
        ssr[wn][wm * 32 + m * 16 + lhi * 4 + j] = pr[m][j];
  }
  __syncthreads();
#pragma unroll
  for (int m = 0; m < 2; ++m)
#pragma unroll
    for (int j = 0; j < 4; ++j) {
      int t = wm * 32 + m * 16 + lhi * 4 + j;
      float ss = ssr[0][t] + ssr[1][t];
      float r = 1.f / sqrtf(ss * (1.f / 128.f) + 1e-6f);
      const float* zp = qkvz + (size_t)(l0 + t) * QZD + CONVD + h * 128;
      u16* dst = gn + (size_t)(l0 + t) * VALD + h * 128;
#pragma unroll
      for (int n = 0; n < 4; ++n) {
        int dv = wn * 64 + n * 16 + l15;
        float z = zp[dv];
        float sil = z / (1.f + expf(-z));
        dst[dv] = f2bf(acc[m][n][j] * r * norm_w[dv] * sil);
      }
    }
}

extern "C" void kernel_launch(void* const* d_in, const int* in_sizes, int n_in,
                              void* d_out, int out_size, void* d_ws, size_t ws_size,
                              hipStream_t stream) {
  const float* x      = (const float*)d_in[0];
  const float* Wqkv   = (const float*)d_in[1];
  const float* Wz     = (const float*)d_in[2];
  const float* Wb     = (const float*)d_in[3];
  const float* Wa     = (const float*)d_in[4];
  const float* conv_w = (const float*)d_in[5];
  const float* A_log  = (const float*)d_in[6];
  const float* dt_bias= (const float*)d_in[7];
  const float* norm_w = (const float*)d_in[8];
  const float* Wout   = (const float*)d_in[9];
  float* out = (float*)d_out;

  char* ws = (char*)d_ws;
  size_t off = 0;
  auto alloc = [&](size_t bytes) {
    void* p = ws + off;
    off = (off + bytes + 255) & ~(size_t)255;
    return p;
  };
  u16* xb     = (u16*)alloc((size_t)L_SEQ * IDIM_ * 2);
  u16* WcatT  = (u16*)alloc((size_t)QZD * IDIM_ * 2);
  u16* WoutT  = (u16*)alloc((size_t)IDIM_ * VALD * 2);
  float* qkvz = (float*)alloc((size_t)L_SEQ * QZD * 4);
  float* qn   = (float*)alloc((size_t)H_ * L_SEQ * 128 * 4);
  float* kn   = (float*)alloc((size_t)H_ * L_SEQ * 128 * 4);
  float* vT   = (float*)alloc((size_t)H_ * 128 * L_SEQ * 4);
  float* btT  = (float*)alloc((size_t)L_SEQ * H_ * 4);
  float* egT  = (float*)alloc((size_t)L_SEQ * H_ * 4);
  float* gTb  = (float*)alloc((size_t)L_SEQ * H_ * 4);
  float* Mb   = (float*)alloc((size_t)NSC * H_ * 128 * 128 * 4);  // 16MB
  float* DbT  = (float*)alloc((size_t)H_ * 128 * L_SEQ * 4);      // 8MB
  u16* gn     = (u16*)alloc((size_t)L_SEQ * VALD * 2);

  // merged casts/transposes + gate-weight rows + zero pad (1 launch)
  prepcast_kernel<<<22616, 256, 0, stream>>>(x, Wqkv, Wz, Wb, Wa, Wout, xb, WcatT, WoutT);

  // combined projection [qkv | z | gates] (65 x 8 tiles)
  gemm_bt_kernel<<<dim3(QZD / 128, L_SEQ / 128), 256, 0, stream>>>(xb, WcatT, qkvz, L_SEQ, QZD, IDIM_);

  // gates from qkvz gate columns (tiny)
  gatelite_kernel<<<64, 256, 0, stream>>>(qkvz, A_log, dt_bias, btT, egT, gTb);

  // merged prep2 (1 launch)
  prep2_kernel<<<6144, 256, 0, stream>>>(qkvz, conv_w, qn, kn, vT);

  // sequential scan: recurrence only (delta^T + boundary states)
  scan_kernel<<<H_ * (DV_ / 16), 256, 0, stream>>>(kn, vT, egT, btT, Mb, DbT);

  // MFMA output reconstruction + fused gated RMSNorm (256 blocks = 1/CU)
  opass_kernel<<<NSC * H_, 256, 0, stream>>>(qn, kn, DbT, gTb, Mb, qkvz, norm_w, gn);

  // final projection, XCD-chunked (256 blocks)
  gemm_bt64_kernel<<<256, 256, 0, stream>>>(gn, WoutT, out, L_SEQ, IDIM_, VALD, 1);
}

// Round 22
// 305.740 us; speedup vs baseline: 1.1879x; 1.0529x over previous
//
#include <hip/hip_runtime.h>

typedef short bf16x8 __attribute__((ext_vector_type(8)));
typedef float f32x4 __attribute__((ext_vector_type(4)));
typedef float f32x2 __attribute__((ext_vector_type(2)));
typedef unsigned short u16;
typedef u16 u16x4 __attribute__((ext_vector_type(4)));

#define L_SEQ 1024
#define IDIM_ 2048
#define H_ 16
#define DK_ 128
#define DV_ 128
#define KEYD 2048
#define VALD 2048
#define CONVD 6144
#define QZD 8320          // qkv(6144) | z(2048) | b(16) | a(16) | pad(96)
#define GCOL 8192
#define SCH 64
#define NSC (L_SEQ / SCH)

__device__ __forceinline__ u16 f2bf(float f) {
  union { float f; unsigned u; } v; v.f = f;
  unsigned r = v.u + 0x7FFF + ((v.u >> 16) & 1);  // RNE
  return (u16)(r >> 16);
}

// 16-lane allreduce, all-DPP. Verified R3-R21.
__device__ __forceinline__ float red16(float x) {
  union U { float f; int i; } a, t;
  a.f = x;
  t.i = __builtin_amdgcn_update_dpp(0, a.i, 0xB1, 0xF, 0xF, true); a.f += t.f;
  t.i = __builtin_amdgcn_update_dpp(0, a.i, 0x4E, 0xF, 0xF, true); a.f += t.f;
  t.i = __builtin_amdgcn_update_dpp(0, a.i, 0x141, 0xF, 0xF, true); a.f += t.f;
  t.i = __builtin_amdgcn_update_dpp(0, a.i, 0x140, 0xF, 0xF, true); a.f += t.f;
  return a.f;
}

// ---- merged cast/transpose prep (R18-exact) ----
__global__ __launch_bounds__(256) void prepcast_kernel(const float* __restrict__ x,
                                                       const float* __restrict__ Wqkv,
                                                       const float* __restrict__ Wz,
                                                       const float* __restrict__ Wb,
                                                       const float* __restrict__ Wa,
                                                       const float* __restrict__ Wout,
                                                       u16* __restrict__ xb,
                                                       u16* __restrict__ WcatT,
                                                       u16* __restrict__ WoutT) {
  __shared__ float tile[32][33];
  const int bid = blockIdx.x;
  if (bid < 2048) {
    int i = (bid * 256 + threadIdx.x) * 4;
    f32x4 v = *(const f32x4*)&x[i];
    u16x4 o = { f2bf(v[0]), f2bf(v[1]), f2bf(v[2]), f2bf(v[3]) };
    *(u16x4*)&xb[i] = o;
    return;
  }
  if (bid >= 22592) {
    size_t off = (size_t)8224 * IDIM_ + (size_t)(bid - 22592) * 8192 + threadIdx.x * 32;
    u16x4 z = {0, 0, 0, 0};
#pragma unroll
    for (int j = 0; j < 8; ++j) *(u16x4*)&WcatT[off + j * 4] = z;
    return;
  }
  if (bid >= 22528) {
    int by = bid - 22528;
    int r = threadIdx.x >> 3, c8 = threadIdx.x & 7;
    int row = by * 32 + r;
#pragma unroll
    for (int cc = 0; cc < 2; ++cc) {
      int c = cc * 8 + c8;
      WcatT[(size_t)(GCOL + c) * IDIM_ + row]      = f2bf(Wb[(size_t)row * 16 + c]);
      WcatT[(size_t)(GCOL + 16 + c) * IDIM_ + row] = f2bf(Wa[(size_t)row * 16 + c]);
    }
    return;
  }
  const float* W; u16* WT; int R, C, bx, by;
  if (bid < 14336) {
    int t = bid - 2048;  bx = t % 192; by = t / 192;
    W = Wqkv; WT = WcatT; R = IDIM_; C = CONVD;
  } else if (bid < 18432) {
    int t = bid - 14336; bx = t & 63; by = t >> 6;
    W = Wz; WT = WcatT + (size_t)CONVD * IDIM_; R = IDIM_; C = VALD;
  } else {
    int t = bid - 18432; bx = t & 63; by = t >> 6;
    W = Wout; WT = WoutT; R = VALD; C = IDIM_;
  }
  int c0 = bx * 32, r0 = by * 32;
  int tx = threadIdx.x & 31, ty = threadIdx.x >> 5;
#pragma unroll
  for (int j = 0; j < 4; ++j)
    tile[ty + j * 8][tx] = W[(size_t)(r0 + ty + j * 8) * C + c0 + tx];
  __syncthreads();
#pragma unroll
  for (int j = 0; j < 4; ++j)
    WT[(size_t)(c0 + ty + j * 8) * R + r0 + tx] = f2bf(tile[tx][ty + j * 8]);
}

// ---------------- NT GEMM (R18-exact) ----------------
__global__ __launch_bounds__(256) void gemm_bt_kernel(const u16* __restrict__ A,
                                                      const u16* __restrict__ B,
                                                      float* __restrict__ C,
                                                      int M, int N, int K) {
  __shared__ short As[128 * 72];
  __shared__ short Bs[128 * 72];
  const int tid = threadIdx.x;
  const int lane = tid & 63, wave = tid >> 6;
  const int wm = wave >> 1, wn = wave & 1;
  const int m0 = blockIdx.y * 128, n0 = blockIdx.x * 128;
  const int l15 = lane & 15, lhi = lane >> 4;

  f32x4 acc[4][4] = {};

  for (int k0 = 0; k0 < K; k0 += 64) {
    __syncthreads();
#pragma unroll
    for (int i = 0; i < 4; ++i) {
      int chunk = tid + i * 256;
      int row = chunk >> 3;
      int kc = (chunk & 7) * 8;
      *(bf16x8*)&As[row * 72 + kc] =
          *(const bf16x8*)&A[(size_t)(m0 + row) * K + k0 + kc];
      *(bf16x8*)&Bs[row * 72 + kc] =
          *(const bf16x8*)&B[(size_t)(n0 + row) * K + k0 + kc];
    }
    __syncthreads();
#pragma unroll
    for (int kk = 0; kk < 64; kk += 32) {
      const int koff = kk + lhi * 8;
      bf16x8 a[4], b[4];
#pragma unroll
      for (int m = 0; m < 4; ++m)
        a[m] = *(const bf16x8*)&As[(wm * 64 + m * 16 + l15) * 72 + koff];
#pragma unroll
      for (int n = 0; n < 4; ++n)
        b[n] = *(const bf16x8*)&Bs[(wn * 64 + n * 16 + l15) * 72 + koff];
#pragma unroll
      for (int m = 0; m < 4; ++m)
#pragma unroll
        for (int n = 0; n < 4; ++n)
          acc[m][n] = __builtin_amdgcn_mfma_f32_16x16x32_bf16(a[m], b[n], acc[m][n], 0, 0, 0);
    }
  }
#pragma unroll
  for (int m = 0; m < 4; ++m)
#pragma unroll
    for (int n = 0; n < 4; ++n)
#pragma unroll
      for (int j = 0; j < 4; ++j) {
        int row = m0 + wm * 64 + m * 16 + lhi * 4 + j;
        int col = n0 + wn * 64 + n * 16 + l15;
        C[(size_t)row * N + col] = acc[m][n][j];
      }
}

// ---------------- NT GEMM BM=64 (R18-exact) ----------------
__global__ __launch_bounds__(256) void gemm_bt64_kernel(const u16* __restrict__ A,
                                                        const u16* __restrict__ B,
                                                        float* __restrict__ C,
                                                        int M, int N, int K, int cxl) {
  __shared__ short As[64 * 72];
  __shared__ short Bs[128 * 72];
  const int tid = threadIdx.x;
  const int lane = tid & 63, wave = tid >> 6;
  const int wm = wave >> 1, wn = wave & 1;
  const int bid = blockIdx.x;
  const int xcd = bid & 7, bi = bid >> 3;
  const int bx = (xcd << cxl) + (bi & ((1 << cxl) - 1));
  const int by = bi >> cxl;
  const int m0 = by * 64, n0 = bx * 128;
  const int l15 = lane & 15, lhi = lane >> 4;

  f32x4 acc[2][4] = {};

  for (int k0 = 0; k0 < K; k0 += 64) {
    __syncthreads();
#pragma unroll
    for (int i = 0; i < 2; ++i) {
      int chunk = tid + i * 256;
      int row = chunk >> 3;
      int kc = (chunk & 7) * 8;
      *(bf16x8*)&As[row * 72 + kc] =
          *(const bf16x8*)&A[(size_t)(m0 + row) * K + k0 + kc];
    }
#pragma unroll
    for (int i = 0; i < 4; ++i) {
      int chunk = tid + i * 256;
      int row = chunk >> 3;
      int kc = (chunk & 7) * 8;
      *(bf16x8*)&Bs[row * 72 + kc] =
          *(const bf16x8*)&B[(size_t)(n0 + row) * K + k0 + kc];
    }
    __syncthreads();
#pragma unroll
    for (int kk = 0; kk < 64; kk += 32) {
      const int koff = kk + lhi * 8;
      bf16x8 a[2], b[4];
#pragma unroll
      for (int m = 0; m < 2; ++m)
        a[m] = *(const bf16x8*)&As[(wm * 32 + m * 16 + l15) * 72 + koff];
#pragma unroll
      for (int n = 0; n < 4; ++n)
        b[n] = *(const bf16x8*)&Bs[(wn * 64 + n * 16 + l15) * 72 + koff];
#pragma unroll
      for (int m = 0; m < 2; ++m)
#pragma unroll
        for (int n = 0; n < 4; ++n)
          acc[m][n] = __builtin_amdgcn_mfma_f32_16x16x32_bf16(a[m], b[n], acc[m][n], 0, 0, 0);
    }
  }
#pragma unroll
  for (int m = 0; m < 2; ++m)
#pragma unroll
    for (int n = 0; n < 4; ++n)
#pragma unroll
      for (int j = 0; j < 4; ++j) {
        int row = m0 + wm * 32 + m * 16 + lhi * 4 + j;
        int col = n0 + wn * 64 + n * 16 + l15;
        C[(size_t)row * N + col] = acc[m][n][j];
      }
}

// -------- gatelite (R18-exact) --------
__global__ __launch_bounds__(256) void gatelite_kernel(const float* __restrict__ qkvz,
                                                       const float* __restrict__ A_log,
                                                       const float* __restrict__ dt_bias,
                                                       float* __restrict__ btT,
                                                       float* __restrict__ gT) {
  int gid = blockIdx.x * 256 + threadIdx.x;
  int l = gid >> 4, h = gid & 15;
  const float* row = qkvz + (size_t)l * QZD + GCOL;
  float b = row[h], a = row[16 + h];
  btT[h * L_SEQ + l] = 1.f / (1.f + expf(-b));
  float dtv = a + dt_bias[h];
  dtv = (dtv > 20.f) ? dtv : log1pf(expf(dtv));
  gT[h * L_SEQ + l] = -expf(A_log[h]) * dtv;
}

// ---- merged prep2 (R18-exact) ----
__global__ __launch_bounds__(256) void prep2_kernel(const float* __restrict__ qkvz,
                                                    const float* __restrict__ cw,
                                                    float* __restrict__ qn,
                                                    float* __restrict__ kn,
                                                    float* __restrict__ vT) {
  __shared__ float tile[32][33];
  const int bid = blockIdx.x;
  if (bid < 4096) {
    int wid = bid * 4 + (threadIdx.x >> 6);
    int lane = threadIdx.x & 63;
    int l = wid >> 4, h = wid & 15;
    const int cq = h * 128 + lane * 2;
    const int ck = KEYD + cq;
    const float* row0 = qkvz + (size_t)l * QZD;
    f32x4 wq0 = *(const f32x4*)&cw[cq * 4];
    f32x4 wq1 = *(const f32x4*)&cw[(cq + 1) * 4];
    f32x4 wk0 = *(const f32x4*)&cw[ck * 4];
    f32x4 wk1 = *(const f32x4*)&cw[(ck + 1) * 4];
    f32x2 xq = *(const f32x2*)&row0[cq];
    f32x2 xk = *(const f32x2*)&row0[ck];
    float q0 = xq[0] * wq0[3], q1 = xq[1] * wq1[3];
    float k0 = xk[0] * wk0[3], k1 = xk[1] * wk1[3];
    if (l >= 1) {
      f32x2 aq = *(const f32x2*)&row0[cq - QZD];
      f32x2 ak = *(const f32x2*)&row0[ck - QZD];
      q0 += aq[0] * wq0[2]; q1 += aq[1] * wq1[2];
      k0 += ak[0] * wk0[2]; k1 += ak[1] * wk1[2];
    }
    if (l >= 2) {
      f32x2 aq = *(const f32x2*)&row0[cq - 2 * QZD];
      f32x2 ak = *(const f32x2*)&row0[ck - 2 * QZD];
      q0 += aq[0] * wq0[1]; q1 += aq[1] * wq1[1];
      k0 += ak[0] * wk0[1]; k1 += ak[1] * wk1[1];
    }
    if (l >= 3) {
      f32x2 aq = *(const f32x2*)&row0[cq - 3 * QZD];
      f32x2 ak = *(const f32x2*)&row0[ck - 3 * QZD];
      q0 += aq[0] * wq0[0]; q1 += aq[1] * wq1[0];
      k0 += ak[0] * wk0[0]; k1 += ak[1] * wk1[0];
    }
    f32x2 qv = { q0 / (1.f + expf(-q0)), q1 / (1.f + expf(-q1)) };
    f32x2 kv = { k0 / (1.f + expf(-k0)), k1 / (1.f + expf(-k1)) };

    float ssq = qv[0] * qv[0] + qv[1] * qv[1];
    float ssk = kv[0] * kv[0] + kv[1] * kv[1];
#pragma unroll
    for (int s = 1; s < 64; s <<= 1) {
      ssq += __shfl_xor(ssq, s);
      ssk += __shfl_xor(ssk, s);
    }
    float scq = 0.08838834764831845f / sqrtf(ssq + 1e-6f);
    float sck = 1.f / sqrtf(ssk + 1e-6f);
    qv[0] *= scq; qv[1] *= scq;
    kv[0] *= sck; kv[1] *= sck;
    size_t base = ((size_t)h * L_SEQ + l) * 128 + lane * 2;
    *(f32x2*)&qn[base] = qv;
    *(f32x2*)&kn[base] = kv;
    return;
  }
  int t = bid - 4096;
  int c0 = (t & 63) * 32, l0 = (t >> 6) * 32;
  int tx = threadIdx.x & 31, ty = threadIdx.x >> 5;
  const int c = 2 * KEYD + c0 + tx;
  f32x4 w = *(const f32x4*)&cw[c * 4];
#pragma unroll
  for (int j = 0; j < 4; ++j) {
    int l = l0 + ty + j * 8;
    const float* p = qkvz + (size_t)l * QZD + c;
    float s = p[0] * w[3];
    if (l >= 1) s += p[-QZD] * w[2];
    if (l >= 2) s += p[-2 * QZD] * w[1];
    if (l >= 3) s += p[-3 * QZD] * w[0];
    tile[ty + j * 8][tx] = s / (1.f + expf(-s));
  }
  __syncthreads();
#pragma unroll
  for (int j = 0; j < 4; ++j)
    vT[(size_t)(c0 + ty + j * 8) * L_SEQ + l0 + tx] = tile[tx][ty + j * 8];
}

// ---------------- winv (R19/R20-exact, verified passing) ----------
// Output Wg[(c*16+h)*4096 + j*64 + s] = W[s][j].
__global__ __launch_bounds__(256) void winv_kernel(const float* __restrict__ kn,
                                                   const float* __restrict__ gT,
                                                   const float* __restrict__ btT,
                                                   float* __restrict__ Wg) {
  __shared__ alignas(16) u16 kb[64][136];
  __shared__ float Nl[64][65];
  __shared__ float gsh[64], Gh[64], bts[64];

  const int tid = threadIdx.x;
  const int lane = tid & 63, wave = tid >> 6;
  const int l15 = lane & 15, lhi = lane >> 4;
  const int h = blockIdx.x & 15, sc = blockIdx.x >> 4;
  const int l0 = sc * SCH;

  {
    int t = tid >> 2, c0 = (tid & 3) * 32;
    const float* kr = kn + ((size_t)h * L_SEQ + l0 + t) * 128 + c0;
#pragma unroll
    for (int j = 0; j < 8; ++j) {
      f32x4 vk = *(const f32x4*)&kr[j * 4];
      u16x4 ok = { f2bf(vk[0]), f2bf(vk[1]), f2bf(vk[2]), f2bf(vk[3]) };
      *(u16x4*)&kb[t][c0 + j * 4] = ok;
    }
  }
  if (tid < 64) {
    gsh[tid] = gT[h * L_SEQ + l0 + tid];
    bts[tid] = btT[h * L_SEQ + l0 + tid];
  }
  __syncthreads();
  if (tid < 64) {
    float a = 0.f;
    for (int u = 0; u <= tid; ++u) a += gsh[u];
    Gh[tid] = a;
  }
  __syncthreads();

  f32x4 acc1[2][2] = {};
  const int wm = wave >> 1, wn = wave & 1;
#pragma unroll
  for (int kk = 0; kk < 128; kk += 32) {
    const int koff = kk + lhi * 8;
    bf16x8 a[2], b[2];
#pragma unroll
    for (int m = 0; m < 2; ++m)
      a[m] = *(const bf16x8*)&kb[wm * 32 + m * 16 + l15][koff];
#pragma unroll
    for (int n = 0; n < 2; ++n)
      b[n] = *(const bf16x8*)&kb[wn * 32 + n * 16 + l15][koff];
#pragma unroll
    for (int m = 0; m < 2; ++m)
#pragma unroll
      for (int n = 0; n < 2; ++n)
        acc1[m][n] = __builtin_amdgcn_mfma_f32_16x16x32_bf16(a[m], b[n], acc1[m][n], 0, 0, 0);
  }
#pragma unroll
  for (int m = 0; m < 2; ++m)
#pragma unroll
    for (int n = 0; n < 2; ++n)
#pragma unroll
      for (int j = 0; j < 4; ++j) {
        int t = wm * 32 + m * 16 + lhi * 4 + j;
        int s = wn * 32 + n * 16 + l15;
        Nl[t][s] = (s < t) ? bts[t] * expf(Gh[t] - Gh[s]) * acc1[m][n][j] : 0.f;
      }
  __syncthreads();

  if (wave == 0) {
    float w[64];
    w[0] = (lane == 0) ? 1.f : 0.f;
#pragma unroll
    for (int t = 1; t < 64; ++t) {
      float a0 = (lane == t) ? 1.f : 0.f, a1 = 0.f;
#pragma unroll
      for (int s = 0; s + 1 < t; s += 2) {
        a0 = fmaf(-Nl[t][s], w[s], a0);
        a1 = fmaf(-Nl[t][s + 1], w[s + 1], a1);
      }
      if (t & 1) a0 = fmaf(-Nl[t][t - 1], w[t - 1], a0);
      w[t] = a0 + a1;
    }
    size_t base = (size_t)(sc * 16 + h) * 4096 + (size_t)lane * 64;
#pragma unroll
    for (int s = 0; s < 64; ++s) Wg[base + s] = w[s];
  }
}

// ---------------- wyscan v3: MFMA chunk recurrence, dv-split 4x ----------
// Grid 64 = 16 heads x 4 dv-slabs of 32. Per chunk (R20-verified math, re-tiled):
//   KM = K@M_in (64x32,K=128), r=beta(v-e^Gh KM) -> rTb
//   delta = W@r (64x32,K=64) -> DbT f32 + ddT (decayed bf16)
//   M = E63*M + K^T@ddT (128x32,K=64); Mreg f32 master + MbfT bf16 mirror.
// Vectorized f32x4 global staging (R20's scalar loads were the 8.5us/chunk cost).
__global__ __launch_bounds__(256) void wyscan_kernel(const float* __restrict__ kn,
                                                     const float* __restrict__ vT,
                                                     const float* __restrict__ gT,
                                                     const float* __restrict__ btT,
                                                     const float* __restrict__ Wg,
                                                     float* __restrict__ Mb,
                                                     float* __restrict__ DbT) {
  __shared__ alignas(16) u16 kb[64][136];     // [t][dk]   A for KM
  __shared__ alignas(16) u16 kbT[128][72];    // [dk][s]   A for M-update
  __shared__ alignas(16) u16 Wbf[64][72];     // [t][s]    A for delta
  __shared__ alignas(16) u16 rTb[32][72];     // [dv][s]   B for delta
  __shared__ alignas(16) u16 ddT[32][72];     // [dv][s]   B for M-update
  __shared__ alignas(16) u16 MbfT[32][136];   // [dv][dk]  B for KM
  __shared__ float gsh[64], Gh[64], bts[64];

  const int tid = threadIdx.x;
  const int lane = tid & 63, wave = tid >> 6;
  const int l15 = lane & 15, lhi = lane >> 4;
  const int wm = wave >> 1, wn = wave & 1;
  const int h = blockIdx.x & 15, slab = blockIdx.x >> 4;
  const int dv0 = slab * 32;
  const int dvl = wn * 16 + l15;              // this lane's local dv column

  for (int i = tid; i < 32 * 136; i += 256) (&MbfT[0][0])[i] = 0;
  f32x4 Mreg[4];
#pragma unroll
  for (int m = 0; m < 4; ++m) Mreg[m] = (f32x4){0.f, 0.f, 0.f, 0.f};
  __syncthreads();

#pragma unroll 1
  for (int c = 0; c < NSC; ++c) {
    const int l0 = c * SCH;
    // dump M_in (chunk-entry state), rows dv global, dk contiguous
#pragma unroll
    for (int m = 0; m < 4; ++m) {
      int dk0 = wm * 64 + m * 16 + lhi * 4;
      *(f32x4*)&Mb[(((size_t)(c * 16 + h)) * 128 + dv0 + dvl) * 128 + dk0] = Mreg[m];
    }
    __syncthreads();   // prev chunk's LDS reads complete before restage

    // stage k: vectorized f32x4 loads, dual LDS layouts from registers
    {
      int t = tid >> 2, c0 = (tid & 3) * 32;
      const float* kr = kn + ((size_t)h * L_SEQ + l0 + t) * 128 + c0;
#pragma unroll
      for (int j4 = 0; j4 < 8; ++j4) {
        f32x4 v = *(const f32x4*)&kr[j4 * 4];
        u16x4 o = { f2bf(v[0]), f2bf(v[1]), f2bf(v[2]), f2bf(v[3]) };
        *(u16x4*)&kb[t][c0 + j4 * 4] = o;
        kbT[c0 + j4 * 4 + 0][t] = o[0];
        kbT[c0 + j4 * 4 + 1][t] = o[1];
        kbT[c0 + j4 * 4 + 2][t] = o[2];
        kbT[c0 + j4 * 4 + 3][t] = o[3];
      }
    }
    // stage W: Wg[base + s*64 + t] = W[t][s]; vectorize over t
    {
      size_t base = (size_t)(c * 16 + h) * 4096;
#pragma unroll
      for (int i = 0; i < 4; ++i) {
        int flat = tid + i * 256;           // 0..1023
        int s = flat >> 4, t0 = (flat & 15) * 4;
        f32x4 v = *(const f32x4*)&Wg[base + (size_t)s * 64 + t0];
        Wbf[t0 + 0][s] = f2bf(v[0]);
        Wbf[t0 + 1][s] = f2bf(v[1]);
        Wbf[t0 + 2][s] = f2bf(v[2]);
        Wbf[t0 + 3][s] = f2bf(v[3]);
      }
    }
    if (tid < 64) {
      gsh[tid] = gT[h * L_SEQ + l0 + tid];
      bts[tid] = btT[h * L_SEQ + l0 + tid];
    }
    __syncthreads();
    if (tid < 64) {
      float a = 0.f;
      for (int u = 0; u <= tid; ++u) a += gsh[u];
      Gh[tid] = a;
    }
    __syncthreads();

    // ---- KM = K @ M_in (64x32, K=128); r = beta(v - e^Gh*KM) -> rTb ----
    {
      f32x4 acc[2] = {};
#pragma unroll
      for (int kk = 0; kk < 128; kk += 32) {
        const int koff = kk + lhi * 8;
        bf16x8 b0 = *(const bf16x8*)&MbfT[dvl][koff];
#pragma unroll
        for (int m = 0; m < 2; ++m) {
          bf16x8 a = *(const bf16x8*)&kb[wm * 32 + m * 16 + l15][koff];
          acc[m] = __builtin_amdgcn_mfma_f32_16x16x32_bf16(a, b0, acc[m], 0, 0, 0);
        }
      }
#pragma unroll
      for (int m = 0; m < 2; ++m) {
        int t0 = wm * 32 + m * 16 + lhi * 4;
        f32x4 v4 = *(const f32x4*)&vT[(size_t)(h * 128 + dv0 + dvl) * L_SEQ + l0 + t0];
#pragma unroll
        for (int j = 0; j < 4; ++j) {
          int t = t0 + j;
          float r = bts[t] * (v4[j] - expf(Gh[t]) * acc[m][j]);
          rTb[dvl][t] = f2bf(r);
        }
      }
    }
    __syncthreads();

    // ---- delta = W @ r (64x32, K=64) -> DbT f32; decayed -> ddT bf16 ----
    {
      f32x4 acc[2] = {};
#pragma unroll
      for (int kk = 0; kk < 64; kk += 32) {
        const int koff = kk + lhi * 8;
        bf16x8 b0 = *(const bf16x8*)&rTb[dvl][koff];
#pragma unroll
        for (int m = 0; m < 2; ++m) {
          bf16x8 a = *(const bf16x8*)&Wbf[wm * 32 + m * 16 + l15][koff];
          acc[m] = __builtin_amdgcn_mfma_f32_16x16x32_bf16(a, b0, acc[m], 0, 0, 0);
        }
      }
      const float G63 = Gh[63];
#pragma unroll
      for (int m = 0; m < 2; ++m) {
        int t0 = wm * 32 + m * 16 + lhi * 4;
        *(f32x4*)&DbT[(size_t)(h * 128 + dv0 + dvl) * L_SEQ + l0 + t0] = acc[m];
#pragma unroll
        for (int j = 0; j < 4; ++j) {
          int t = t0 + j;
          ddT[dvl][t] = f2bf(acc[m][j] * expf(G63 - Gh[t]));
        }
      }
    }
    __syncthreads();

    // ---- M = E63*M + K^T @ ddT (128x32, K=64); refresh bf16 mirror ----
    {
      const float E63 = expf(Gh[63]);
      f32x4 acc[4];
#pragma unroll
      for (int m = 0; m < 4; ++m)
#pragma unroll
        for (int j = 0; j < 4; ++j) acc[m][j] = E63 * Mreg[m][j];
#pragma unroll
      for (int kk = 0; kk < 64; kk += 32) {
        const int koff = kk + lhi * 8;
        bf16x8 b0 = *(const bf16x8*)&ddT[dvl][koff];
#pragma unroll
        for (int m = 0; m < 4; ++m) {
          bf16x8 a = *(const bf16x8*)&kbT[wm * 64 + m * 16 + l15][koff];
          acc[m] = __builtin_amdgcn_mfma_f32_16x16x32_bf16(a, b0, acc[m], 0, 0, 0);
        }
      }
#pragma unroll
      for (int m = 0; m < 4; ++m) {
        Mreg[m] = acc[m];
        int dk0 = wm * 64 + m * 16 + lhi * 4;
#pragma unroll
        for (int j = 0; j < 4; ++j)
          MbfT[dvl][dk0 + j] = f2bf(acc[m][j]);
      }
    }
    __syncthreads();
  }
}

// ---------------- MFMA output reconstruction + fused gated RMSNorm (R18-exact) ----
__global__ __launch_bounds__(256) void opass_kernel(const float* __restrict__ qn,
                                                    const float* __restrict__ kn,
                                                    const float* __restrict__ DbT,
                                                    const float* __restrict__ gT,
                                                    const float* __restrict__ Mb,
                                                    const float* __restrict__ qkvz,
                                                    const float* __restrict__ norm_w,
                                                    u16* __restrict__ gn) {
  __shared__ alignas(16) u16 qsb[64][136];
  __shared__ alignas(16) u16 bbuf[128][136];
  __shared__ alignas(16) u16 Asb[64][72];
  __shared__ float gsh[64], Gh[64];
  __shared__ float ssr[2][64];

  const int tid = threadIdx.x;
  const int lane = tid & 63, wave = tid >> 6;
  const int l15 = lane & 15, lhi = lane >> 4;
  const int h = blockIdx.x & 15, sc = blockIdx.x >> 4;
  const int l0 = sc * SCH;

  {
    int t = tid >> 2, c0 = (tid & 3) * 32;
    const float* qr = qn + ((size_t)h * L_SEQ + l0 + t) * 128 + c0;
    const float* kr = kn + ((size_t)h * L_SEQ + l0 + t) * 128 + c0;
#pragma unroll
    for (int j = 0; j < 8; ++j) {
      f32x4 vq = *(const f32x4*)&qr[j * 4];
      f32x4 vk = *(const f32x4*)&kr[j * 4];
      u16x4 oq = { f2bf(vq[0]), f2bf(vq[1]), f2bf(vq[2]), f2bf(vq[3]) };
      u16x4 ok = { f2bf(vk[0]), f2bf(vk[1]), f2bf(vk[2]), f2bf(vk[3]) };
      *(u16x4*)&qsb[t][c0 + j * 4] = oq;
      *(u16x4*)&bbuf[t][c0 + j * 4] = ok;
    }
  }
  if (tid < 64) gsh[tid] = gT[h * L_SEQ + l0 + tid];
  __syncthreads();
  if (tid < 64) {
    float a = 0.f;
    for (int u = 0; u <= tid; ++u) a += gsh[u];
    Gh[tid] = a;
  }
  __syncthreads();

  f32x4 acc1[2][2] = {};
  const int wm = wave >> 1, wn = wave & 1;
#pragma unroll
  for (int kk = 0; kk < 128; kk += 32) {
    const int koff = kk + lhi * 8;
    bf16x8 a[2], b[2];
#pragma unroll
    for (int m = 0; m < 2; ++m)
      a[m] = *(const bf16x8*)&qsb[wm * 32 + m * 16 + l15][koff];
#pragma unroll
    for (int n = 0; n < 2; ++n)
      b[n] = *(const bf16x8*)&bbuf[wn * 32 + n * 16 + l15][koff];
#pragma unroll
    for (int m = 0; m < 2; ++m)
#pragma unroll
      for (int n = 0; n < 2; ++n)
        acc1[m][n] = __builtin_amdgcn_mfma_f32_16x16x32_bf16(a[m], b[n], acc1[m][n], 0, 0, 0);
  }
#pragma unroll
  for (int m = 0; m < 2; ++m)
#pragma unroll
    for (int n = 0; n < 2; ++n)
#pragma unroll
      for (int j = 0; j < 4; ++j) {
        int t = wm * 32 + m * 16 + lhi * 4 + j;
        int s = wn * 32 + n * 16 + l15;
        float a = (s <= t) ? acc1[m][n][j] * expf(Gh[t] - Gh[s]) : 0.f;
        Asb[t][s] = f2bf(a);
      }
  __syncthreads();

  {
    int dv = tid >> 1, c0 = (tid & 1) * 64;
    const float* mr = Mb + (((size_t)sc * 16 + h) * 128 + dv) * 128 + c0;
#pragma unroll
    for (int j = 0; j < 16; ++j) {
      f32x4 v = *(const f32x4*)&mr[j * 4];
      u16x4 o = { f2bf(v[0]), f2bf(v[1]), f2bf(v[2]), f2bf(v[3]) };
      *(u16x4*)&bbuf[dv][c0 + j * 4] = o;
    }
  }
  __syncthreads();

  f32x4 acc[2][4] = {};
#pragma unroll
  for (int kk = 0; kk < 128; kk += 32) {
    const int koff = kk + lhi * 8;
    bf16x8 a[2], b[4];
#pragma unroll
    for (int m = 0; m < 2; ++m)
      a[m] = *(const bf16x8*)&qsb[wm * 32 + m * 16 + l15][koff];
#pragma unroll
    for (int n = 0; n < 4; ++n)
      b[n] = *(const bf16x8*)&bbuf[wn * 64 + n * 16 + l15][koff];
#pragma unroll
    for (int m = 0; m < 2; ++m)
#pragma unroll
      for (int n = 0; n < 4; ++n)
        acc[m][n] = __builtin_amdgcn_mfma_f32_16x16x32_bf16(a[m], b[n], acc[m][n], 0, 0, 0);
  }
#pragma unroll
  for (int m = 0; m < 2; ++m) {
#pragma unroll
    for (int j = 0; j < 4; ++j) {
      int t = wm * 32 + m * 16 + lhi * 4 + j;
      float sc1 = expf(Gh[t]);
#pragma unroll
      for (int n = 0; n < 4; ++n) acc[m][n][j] *= sc1;
    }
  }
  __syncthreads();

  {
    int dv = tid >> 1, c0 = (tid & 1) * 32;
    const float* dr = DbT + (size_t)(h * 128 + dv) * L_SEQ + l0 + c0;
#pragma unroll
    for (int j = 0; j < 8; ++j) {
      f32x4 v = *(const f32x4*)&dr[j * 4];
      u16x4 o = { f2bf(v[0]), f2bf(v[1]), f2bf(v[2]), f2bf(v[3]) };
      *(u16x4*)&bbuf[dv][c0 + j * 4] = o;
    }
  }
  __syncthreads();

#pragma unroll
  for (int kk = 0; kk < 64; kk += 32) {
    const int koff = kk + lhi * 8;
    bf16x8 a[2], b[4];
#pragma unroll
    for (int m = 0; m < 2; ++m)
      a[m] = *(const bf16x8*)&Asb[wm * 32 + m * 16 + l15][koff];
#pragma unroll
    for (int n = 0; n < 4; ++n)
      b[n] = *(const bf16x8*)&bbuf[wn * 64 + n * 16 + l15][koff];
#pragma unroll
    for (int m = 0; m < 2; ++m)
#pragma unroll
      for (int n = 0; n < 4; ++n)
        acc[m][n] = __builtin_amdgcn_mfma_f32_16x16x32_bf16(a[m], b[n], acc[m][n], 0, 0, 0);
  }

  float pr[2][4];
#pragma unroll
  for (int m = 0; m < 2; ++m)
#pragma unroll
    for (int j = 0; j < 4; ++j) {
      float p = 0.f;
#pragma unroll
      for (int n = 0; n < 4; ++n) p = fmaf(acc[m][n][j], acc[m][n][j], p);
      pr[m][j] = red16(p);
    }
  if (l15 == 0) {
#pragma unroll
    for (int m = 0; m < 2; ++m)
#pragma unroll
      for (int j = 0; j < 4; ++j)
        ssr[wn][wm * 32 + m * 16 + lhi * 4 + j] = pr[m][j];
  }
  __syncthreads();
#pragma unroll
  for (int m = 0; m < 2; ++m)
#pragma unroll
    for (int j = 0; j < 4; ++j) {
      int t = wm * 32 + m * 16 + lhi * 4 + j;
      float ss = ssr[0][t] + ssr[1][t];
      float r = 1.f / sqrtf(ss * (1.f / 128.f) + 1e-6f);
      const float* zp = qkvz + (size_t)(l0 + t) * QZD + CONVD + h * 128;
      u16* dst = gn + (size_t)(l0 + t) * VALD + h * 128;
#pragma unroll
      for (int n = 0; n < 4; ++n) {
        int dv = wn * 64 + n * 16 + l15;
        float z = zp[dv];
        float sil = z / (1.f + expf(-z));
        dst[dv] = f2bf(acc[m][n][j] * r * norm_w[dv] * sil);
      }
    }
}

extern "C" void kernel_launch(void* const* d_in, const int* in_sizes, int n_in,
                              void* d_out, int out_size, void* d_ws, size_t ws_size,
                              hipStream_t stream) {
  const float* x      = (const float*)d_in[0];
  const float* Wqkv   = (const float*)d_in[1];
  const float* Wz     = (const float*)d_in[2];
  const float* Wb     = (const float*)d_in[3];
  const float* Wa     = (const float*)d_in[4];
  const float* conv_w = (const float*)d_in[5];
  const float* A_log  = (const float*)d_in[6];
  const float* dt_bias= (const float*)d_in[7];
  const float* norm_w = (const float*)d_in[8];
  const float* Wout   = (const float*)d_in[9];
  float* out = (float*)d_out;

  char* ws = (char*)d_ws;
  size_t off = 0;
  auto alloc = [&](size_t bytes) {
    void* p = ws + off;
    off = (off + bytes + 255) & ~(size_t)255;
    return p;
  };
  u16* xb     = (u16*)alloc((size_t)L_SEQ * IDIM_ * 2);
  u16* WcatT  = (u16*)alloc((size_t)QZD * IDIM_ * 2);
  u16* WoutT  = (u16*)alloc((size_t)IDIM_ * VALD * 2);
  float* qkvz = (float*)alloc((size_t)L_SEQ * QZD * 4);
  float* qn   = (float*)alloc((size_t)H_ * L_SEQ * 128 * 4);
  float* kn   = (float*)alloc((size_t)H_ * L_SEQ * 128 * 4);
  float* vT   = (float*)alloc((size_t)H_ * 128 * L_SEQ * 4);
  float* btT  = (float*)alloc((size_t)L_SEQ * H_ * 4);
  float* gTb  = (float*)alloc((size_t)L_SEQ * H_ * 4);
  float* Wgb  = (float*)alloc((size_t)NSC * H_ * 64 * 64 * 4);    // 4MB
  float* Mb   = (float*)alloc((size_t)NSC * H_ * 128 * 128 * 4);  // 16MB
  float* DbT  = (float*)alloc((size_t)H_ * 128 * L_SEQ * 4);      // 8MB
  u16* gn     = (u16*)alloc((size_t)L_SEQ * VALD * 2);

  // merged casts/transposes + gate-weight rows + zero pad (1 launch)
  prepcast_kernel<<<22616, 256, 0, stream>>>(x, Wqkv, Wz, Wb, Wa, Wout, xb, WcatT, WoutT);

  // combined projection [qkv | z | gates]
  gemm_bt_kernel<<<dim3(QZD / 128, L_SEQ / 128), 256, 0, stream>>>(xb, WcatT, qkvz, L_SEQ, QZD, IDIM_);

  // gates
  gatelite_kernel<<<64, 256, 0, stream>>>(qkvz, A_log, dt_bias, btT, gTb);

  // merged prep2
  prep2_kernel<<<6144, 256, 0, stream>>>(qkvz, conv_w, qn, kn, vT);

  // chunked-WY scan: W precompute (parallel) + MFMA chunk recurrence (64 blocks)
  winv_kernel<<<NSC * H_, 256, 0, stream>>>(kn, gTb, btT, Wgb);
  wyscan_kernel<<<H_ * 4, 256, 0, stream>>>(kn, vT, gTb, btT, Wgb, Mb, DbT);

  // MFMA output reconstruction + fused gated RMSNorm
  opass_kernel<<<NSC * H_, 256, 0, stream>>>(qn, kn, DbT, gTb, Mb, qkvz, norm_w, gn);

  // final projection
  gemm_bt64_kernel<<<256, 256, 0, stream>>>(gn, WoutT, out, L_SEQ, IDIM_, VALD, 1);
}

// Round 23
// 299.589 us; speedup vs baseline: 1.2123x; 1.0205x over previous
//
#include <hip/hip_runtime.h>

typedef short bf16x8 __attribute__((ext_vector_type(8)));
typedef float f32x4 __attribute__((ext_vector_type(4)));
typedef float f32x2 __attribute__((ext_vector_type(2)));
typedef unsigned short u16;
typedef u16 u16x4 __attribute__((ext_vector_type(4)));

#define L_SEQ 1024
#define IDIM_ 2048
#define H_ 16
#define DK_ 128
#define DV_ 128
#define KEYD 2048
#define VALD 2048
#define CONVD 6144
#define QZD 8320          // qkv(6144) | z(2048) | b(16) | a(16) | pad(96)
#define GCOL 8192
#define SCH 64
#define NSC (L_SEQ / SCH)

__device__ __forceinline__ u16 f2bf(float f) {
  union { float f; unsigned u; } v; v.f = f;
  unsigned r = v.u + 0x7FFF + ((v.u >> 16) & 1);  // RNE
  return (u16)(r >> 16);
}

// 16-lane allreduce, all-DPP. Verified R3-R22.
__device__ __forceinline__ float red16(float x) {
  union U { float f; int i; } a, t;
  a.f = x;
  t.i = __builtin_amdgcn_update_dpp(0, a.i, 0xB1, 0xF, 0xF, true); a.f += t.f;
  t.i = __builtin_amdgcn_update_dpp(0, a.i, 0x4E, 0xF, 0xF, true); a.f += t.f;
  t.i = __builtin_amdgcn_update_dpp(0, a.i, 0x141, 0xF, 0xF, true); a.f += t.f;
  t.i = __builtin_amdgcn_update_dpp(0, a.i, 0x140, 0xF, 0xF, true); a.f += t.f;
  return a.f;
}

// ---- merged cast/transpose prep (R18-exact) ----
__global__ __launch_bounds__(256) void prepcast_kernel(const float* __restrict__ x,
                                                       const float* __restrict__ Wqkv,
                                                       const float* __restrict__ Wz,
                                                       const float* __restrict__ Wb,
                                                       const float* __restrict__ Wa,
                                                       const float* __restrict__ Wout,
                                                       u16* __restrict__ xb,
                                                       u16* __restrict__ WcatT,
                                                       u16* __restrict__ WoutT) {
  __shared__ float tile[32][33];
  const int bid = blockIdx.x;
  if (bid < 2048) {
    int i = (bid * 256 + threadIdx.x) * 4;
    f32x4 v = *(const f32x4*)&x[i];
    u16x4 o = { f2bf(v[0]), f2bf(v[1]), f2bf(v[2]), f2bf(v[3]) };
    *(u16x4*)&xb[i] = o;
    return;
  }
  if (bid >= 22592) {
    size_t off = (size_t)8224 * IDIM_ + (size_t)(bid - 22592) * 8192 + threadIdx.x * 32;
    u16x4 z = {0, 0, 0, 0};
#pragma unroll
    for (int j = 0; j < 8; ++j) *(u16x4*)&WcatT[off + j * 4] = z;
    return;
  }
  if (bid >= 22528) {
    int by = bid - 22528;
    int r = threadIdx.x >> 3, c8 = threadIdx.x & 7;
    int row = by * 32 + r;
#pragma unroll
    for (int cc = 0; cc < 2; ++cc) {
      int c = cc * 8 + c8;
      WcatT[(size_t)(GCOL + c) * IDIM_ + row]      = f2bf(Wb[(size_t)row * 16 + c]);
      WcatT[(size_t)(GCOL + 16 + c) * IDIM_ + row] = f2bf(Wa[(size_t)row * 16 + c]);
    }
    return;
  }
  const float* W; u16* WT; int R, C, bx, by;
  if (bid < 14336) {
    int t = bid - 2048;  bx = t % 192; by = t / 192;
    W = Wqkv; WT = WcatT; R = IDIM_; C = CONVD;
  } else if (bid < 18432) {
    int t = bid - 14336; bx = t & 63; by = t >> 6;
    W = Wz; WT = WcatT + (size_t)CONVD * IDIM_; R = IDIM_; C = VALD;
  } else {
    int t = bid - 18432; bx = t & 63; by = t >> 6;
    W = Wout; WT = WoutT; R = VALD; C = IDIM_;
  }
  int c0 = bx * 32, r0 = by * 32;
  int tx = threadIdx.x & 31, ty = threadIdx.x >> 5;
#pragma unroll
  for (int j = 0; j < 4; ++j)
    tile[ty + j * 8][tx] = W[(size_t)(r0 + ty + j * 8) * C + c0 + tx];
  __syncthreads();
#pragma unroll
  for (int j = 0; j < 4; ++j)
    WT[(size_t)(c0 + ty + j * 8) * R + r0 + tx] = f2bf(tile[tx][ty + j * 8]);
}

// ---------------- NT GEMM (R18-exact) ----------------
__global__ __launch_bounds__(256) void gemm_bt_kernel(const u16* __restrict__ A,
                                                      const u16* __restrict__ B,
                                                      float* __restrict__ C,
                                                      int M, int N, int K) {
  __shared__ short As[128 * 72];
  __shared__ short Bs[128 * 72];
  const int tid = threadIdx.x;
  const int lane = tid & 63, wave = tid >> 6;
  const int wm = wave >> 1, wn = wave & 1;
  const int m0 = blockIdx.y * 128, n0 = blockIdx.x * 128;
  const int l15 = lane & 15, lhi = lane >> 4;

  f32x4 acc[4][4] = {};

  for (int k0 = 0; k0 < K; k0 += 64) {
    __syncthreads();
#pragma unroll
    for (int i = 0; i < 4; ++i) {
      int chunk = tid + i * 256;
      int row = chunk >> 3;
      int kc = (chunk & 7) * 8;
      *(bf16x8*)&As[row * 72 + kc] =
          *(const bf16x8*)&A[(size_t)(m0 + row) * K + k0 + kc];
      *(bf16x8*)&Bs[row * 72 + kc] =
          *(const bf16x8*)&B[(size_t)(n0 + row) * K + k0 + kc];
    }
    __syncthreads();
#pragma unroll
    for (int kk = 0; kk < 64; kk += 32) {
      const int koff = kk + lhi * 8;
      bf16x8 a[4], b[4];
#pragma unroll
      for (int m = 0; m < 4; ++m)
        a[m] = *(const bf16x8*)&As[(wm * 64 + m * 16 + l15) * 72 + koff];
#pragma unroll
      for (int n = 0; n < 4; ++n)
        b[n] = *(const bf16x8*)&Bs[(wn * 64 + n * 16 + l15) * 72 + koff];
#pragma unroll
      for (int m = 0; m < 4; ++m)
#pragma unroll
        for (int n = 0; n < 4; ++n)
          acc[m][n] = __builtin_amdgcn_mfma_f32_16x16x32_bf16(a[m], b[n], acc[m][n], 0, 0, 0);
    }
  }
#pragma unroll
  for (int m = 0; m < 4; ++m)
#pragma unroll
    for (int n = 0; n < 4; ++n)
#pragma unroll
      for (int j = 0; j < 4; ++j) {
        int row = m0 + wm * 64 + m * 16 + lhi * 4 + j;
        int col = n0 + wn * 64 + n * 16 + l15;
        C[(size_t)row * N + col] = acc[m][n][j];
      }
}

// ---------------- NT GEMM BM=64 (R18-exact) ----------------
__global__ __launch_bounds__(256) void gemm_bt64_kernel(const u16* __restrict__ A,
                                                        const u16* __restrict__ B,
                                                        float* __restrict__ C,
                                                        int M, int N, int K, int cxl) {
  __shared__ short As[64 * 72];
  __shared__ short Bs[128 * 72];
  const int tid = threadIdx.x;
  const int lane = tid & 63, wave = tid >> 6;
  const int wm = wave >> 1, wn = wave & 1;
  const int bid = blockIdx.x;
  const int xcd = bid & 7, bi = bid >> 3;
  const int bx = (xcd << cxl) + (bi & ((1 << cxl) - 1));
  const int by = bi >> cxl;
  const int m0 = by * 64, n0 = bx * 128;
  const int l15 = lane & 15, lhi = lane >> 4;

  f32x4 acc[2][4] = {};

  for (int k0 = 0; k0 < K; k0 += 64) {
    __syncthreads();
#pragma unroll
    for (int i = 0; i < 2; ++i) {
      int chunk = tid + i * 256;
      int row = chunk >> 3;
      int kc = (chunk & 7) * 8;
      *(bf16x8*)&As[row * 72 + kc] =
          *(const bf16x8*)&A[(size_t)(m0 + row) * K + k0 + kc];
    }
#pragma unroll
    for (int i = 0; i < 4; ++i) {
      int chunk = tid + i * 256;
      int row = chunk >> 3;
      int kc = (chunk & 7) * 8;
      *(bf16x8*)&Bs[row * 72 + kc] =
          *(const bf16x8*)&B[(size_t)(n0 + row) * K + k0 + kc];
    }
    __syncthreads();
#pragma unroll
    for (int kk = 0; kk < 64; kk += 32) {
      const int koff = kk + lhi * 8;
      bf16x8 a[2], b[4];
#pragma unroll
      for (int m = 0; m < 2; ++m)
        a[m] = *(const bf16x8*)&As[(wm * 32 + m * 16 + l15) * 72 + koff];
#pragma unroll
      for (int n = 0; n < 4; ++n)
        b[n] = *(const bf16x8*)&Bs[(wn * 64 + n * 16 + l15) * 72 + koff];
#pragma unroll
      for (int m = 0; m < 2; ++m)
#pragma unroll
        for (int n = 0; n < 4; ++n)
          acc[m][n] = __builtin_amdgcn_mfma_f32_16x16x32_bf16(a[m], b[n], acc[m][n], 0, 0, 0);
    }
  }
#pragma unroll
  for (int m = 0; m < 2; ++m)
#pragma unroll
    for (int n = 0; n < 4; ++n)
#pragma unroll
      for (int j = 0; j < 4; ++j) {
        int row = m0 + wm * 32 + m * 16 + lhi * 4 + j;
        int col = n0 + wn * 64 + n * 16 + l15;
        C[(size_t)row * N + col] = acc[m][n][j];
      }
}

// -------- gatelite (R18-exact) --------
__global__ __launch_bounds__(256) void gatelite_kernel(const float* __restrict__ qkvz,
                                                       const float* __restrict__ A_log,
                                                       const float* __restrict__ dt_bias,
                                                       float* __restrict__ btT,
                                                       float* __restrict__ gT) {
  int gid = blockIdx.x * 256 + threadIdx.x;
  int l = gid >> 4, h = gid & 15;
  const float* row = qkvz + (size_t)l * QZD + GCOL;
  float b = row[h], a = row[16 + h];
  btT[h * L_SEQ + l] = 1.f / (1.f + expf(-b));
  float dtv = a + dt_bias[h];
  dtv = (dtv > 20.f) ? dtv : log1pf(expf(dtv));
  gT[h * L_SEQ + l] = -expf(A_log[h]) * dtv;
}

// ---- merged prep2 (R18-exact) ----
__global__ __launch_bounds__(256) void prep2_kernel(const float* __restrict__ qkvz,
                                                    const float* __restrict__ cw,
                                                    float* __restrict__ qn,
                                                    float* __restrict__ kn,
                                                    float* __restrict__ vT) {
  __shared__ float tile[32][33];
  const int bid = blockIdx.x;
  if (bid < 4096) {
    int wid = bid * 4 + (threadIdx.x >> 6);
    int lane = threadIdx.x & 63;
    int l = wid >> 4, h = wid & 15;
    const int cq = h * 128 + lane * 2;
    const int ck = KEYD + cq;
    const float* row0 = qkvz + (size_t)l * QZD;
    f32x4 wq0 = *(const f32x4*)&cw[cq * 4];
    f32x4 wq1 = *(const f32x4*)&cw[(cq + 1) * 4];
    f32x4 wk0 = *(const f32x4*)&cw[ck * 4];
    f32x4 wk1 = *(const f32x4*)&cw[(ck + 1) * 4];
    f32x2 xq = *(const f32x2*)&row0[cq];
    f32x2 xk = *(const f32x2*)&row0[ck];
    float q0 = xq[0] * wq0[3], q1 = xq[1] * wq1[3];
    float k0 = xk[0] * wk0[3], k1 = xk[1] * wk1[3];
    if (l >= 1) {
      f32x2 aq = *(const f32x2*)&row0[cq - QZD];
      f32x2 ak = *(const f32x2*)&row0[ck - QZD];
      q0 += aq[0] * wq0[2]; q1 += aq[1] * wq1[2];
      k0 += ak[0] * wk0[2]; k1 += ak[1] * wk1[2];
    }
    if (l >= 2) {
      f32x2 aq = *(const f32x2*)&row0[cq - 2 * QZD];
      f32x2 ak = *(const f32x2*)&row0[ck - 2 * QZD];
      q0 += aq[0] * wq0[1]; q1 += aq[1] * wq1[1];
      k0 += ak[0] * wk0[1]; k1 += ak[1] * wk1[1];
    }
    if (l >= 3) {
      f32x2 aq = *(const f32x2*)&row0[cq - 3 * QZD];
      f32x2 ak = *(const f32x2*)&row0[ck - 3 * QZD];
      q0 += aq[0] * wq0[0]; q1 += aq[1] * wq1[0];
      k0 += ak[0] * wk0[0]; k1 += ak[1] * wk1[0];
    }
    f32x2 qv = { q0 / (1.f + expf(-q0)), q1 / (1.f + expf(-q1)) };
    f32x2 kv = { k0 / (1.f + expf(-k0)), k1 / (1.f + expf(-k1)) };

    float ssq = qv[0] * qv[0] + qv[1] * qv[1];
    float ssk = kv[0] * kv[0] + kv[1] * kv[1];
#pragma unroll
    for (int s = 1; s < 64; s <<= 1) {
      ssq += __shfl_xor(ssq, s);
      ssk += __shfl_xor(ssk, s);
    }
    float scq = 0.08838834764831845f / sqrtf(ssq + 1e-6f);
    float sck = 1.f / sqrtf(ssk + 1e-6f);
    qv[0] *= scq; qv[1] *= scq;
    kv[0] *= sck; kv[1] *= sck;
    size_t base = ((size_t)h * L_SEQ + l) * 128 + lane * 2;
    *(f32x2*)&qn[base] = qv;
    *(f32x2*)&kn[base] = kv;
    return;
  }
  int t = bid - 4096;
  int c0 = (t & 63) * 32, l0 = (t >> 6) * 32;
  int tx = threadIdx.x & 31, ty = threadIdx.x >> 5;
  const int c = 2 * KEYD + c0 + tx;
  f32x4 w = *(const f32x4*)&cw[c * 4];
#pragma unroll
  for (int j = 0; j < 4; ++j) {
    int l = l0 + ty + j * 8;
    const float* p = qkvz + (size_t)l * QZD + c;
    float s = p[0] * w[3];
    if (l >= 1) s += p[-QZD] * w[2];
    if (l >= 2) s += p[-2 * QZD] * w[1];
    if (l >= 3) s += p[-3 * QZD] * w[0];
    tile[ty + j * 8][tx] = s / (1.f + expf(-s));
  }
  __syncthreads();
#pragma unroll
  for (int j = 0; j < 4; ++j)
    vT[(size_t)(c0 + ty + j * 8) * L_SEQ + l0 + tx] = tile[tx][ty + j * 8];
}

// ---------------- winv: now emits bf16 W directly ----------
// Output Wg16[(c*16+h)*4096 + j*64 + s] = f2bf(W[s][j]).
__global__ __launch_bounds__(256) void winv_kernel(const float* __restrict__ kn,
                                                   const float* __restrict__ gT,
                                                   const float* __restrict__ btT,
                                                   u16* __restrict__ Wg16) {
  __shared__ alignas(16) u16 kb[64][136];
  __shared__ float Nl[64][65];
  __shared__ float gsh[64], Gh[64], bts[64];

  const int tid = threadIdx.x;
  const int lane = tid & 63, wave = tid >> 6;
  const int l15 = lane & 15, lhi = lane >> 4;
  const int h = blockIdx.x & 15, sc = blockIdx.x >> 4;
  const int l0 = sc * SCH;

  {
    int t = tid >> 2, c0 = (tid & 3) * 32;
    const float* kr = kn + ((size_t)h * L_SEQ + l0 + t) * 128 + c0;
#pragma unroll
    for (int j = 0; j < 8; ++j) {
      f32x4 vk = *(const f32x4*)&kr[j * 4];
      u16x4 ok = { f2bf(vk[0]), f2bf(vk[1]), f2bf(vk[2]), f2bf(vk[3]) };
      *(u16x4*)&kb[t][c0 + j * 4] = ok;
    }
  }
  if (tid < 64) {
    gsh[tid] = gT[h * L_SEQ + l0 + tid];
    bts[tid] = btT[h * L_SEQ + l0 + tid];
  }
  __syncthreads();
  if (tid < 64) {
    float a = 0.f;
    for (int u = 0; u <= tid; ++u) a += gsh[u];
    Gh[tid] = a;
  }
  __syncthreads();

  f32x4 acc1[2][2] = {};
  const int wm = wave >> 1, wn = wave & 1;
#pragma unroll
  for (int kk = 0; kk < 128; kk += 32) {
    const int koff = kk + lhi * 8;
    bf16x8 a[2], b[2];
#pragma unroll
    for (int m = 0; m < 2; ++m)
      a[m] = *(const bf16x8*)&kb[wm * 32 + m * 16 + l15][koff];
#pragma unroll
    for (int n = 0; n < 2; ++n)
      b[n] = *(const bf16x8*)&kb[wn * 32 + n * 16 + l15][koff];
#pragma unroll
    for (int m = 0; m < 2; ++m)
#pragma unroll
      for (int n = 0; n < 2; ++n)
        acc1[m][n] = __builtin_amdgcn_mfma_f32_16x16x32_bf16(a[m], b[n], acc1[m][n], 0, 0, 0);
  }
#pragma unroll
  for (int m = 0; m < 2; ++m)
#pragma unroll
    for (int n = 0; n < 2; ++n)
#pragma unroll
      for (int j = 0; j < 4; ++j) {
        int t = wm * 32 + m * 16 + lhi * 4 + j;
        int s = wn * 32 + n * 16 + l15;
        Nl[t][s] = (s < t) ? bts[t] * expf(Gh[t] - Gh[s]) * acc1[m][n][j] : 0.f;
      }
  __syncthreads();

  if (wave == 0) {
    float w[64];
    w[0] = (lane == 0) ? 1.f : 0.f;
#pragma unroll
    for (int t = 1; t < 64; ++t) {
      float a0 = (lane == t) ? 1.f : 0.f, a1 = 0.f;
#pragma unroll
      for (int s = 0; s + 1 < t; s += 2) {
        a0 = fmaf(-Nl[t][s], w[s], a0);
        a1 = fmaf(-Nl[t][s + 1], w[s + 1], a1);
      }
      if (t & 1) a0 = fmaf(-Nl[t][t - 1], w[t - 1], a0);
      w[t] = a0 + a1;
    }
    size_t base = (size_t)(sc * 16 + h) * 4096 + (size_t)lane * 64;
#pragma unroll
    for (int s = 0; s < 64; s += 4) {
      u16x4 o = { f2bf(w[s]), f2bf(w[s + 1]), f2bf(w[s + 2]), f2bf(w[s + 3]) };
      *(u16x4*)&Wg16[base + s] = o;
    }
  }
}

// ---------------- wyscan v3 (R22-passing) + bf16 interchange stores ----------
__global__ __launch_bounds__(256) void wyscan_kernel(const float* __restrict__ kn,
                                                     const float* __restrict__ vT,
                                                     const float* __restrict__ gT,
                                                     const float* __restrict__ btT,
                                                     const u16* __restrict__ Wg16,
                                                     u16* __restrict__ MbT,
                                                     u16* __restrict__ DbT16) {
  __shared__ alignas(16) u16 kb[64][136];     // [t][dk]   A for KM
  __shared__ alignas(16) u16 kbT[128][72];    // [dk][s]   A for M-update
  __shared__ alignas(16) u16 Wbf[64][72];     // [t][s]    A for delta
  __shared__ alignas(16) u16 rTb[32][72];     // [dv][s]   B for delta
  __shared__ alignas(16) u16 ddT[32][72];     // [dv][s]   B for M-update
  __shared__ alignas(16) u16 MbfT[32][136];   // [dv][dk]  B for KM
  __shared__ float gsh[64], Gh[64], bts[64];

  const int tid = threadIdx.x;
  const int lane = tid & 63, wave = tid >> 6;
  const int l15 = lane & 15, lhi = lane >> 4;
  const int wm = wave >> 1, wn = wave & 1;
  const int h = blockIdx.x & 15, slab = blockIdx.x >> 4;
  const int dv0 = slab * 32;
  const int dvl = wn * 16 + l15;              // this lane's local dv column

  for (int i = tid; i < 32 * 136; i += 256) (&MbfT[0][0])[i] = 0;
  f32x4 Mreg[4];
#pragma unroll
  for (int m = 0; m < 4; ++m) Mreg[m] = (f32x4){0.f, 0.f, 0.f, 0.f};
  __syncthreads();

#pragma unroll 1
  for (int c = 0; c < NSC; ++c) {
    const int l0 = c * SCH;
    // dump M_in (chunk-entry state) as bf16 (same f2bf values as the mirror)
#pragma unroll
    for (int m = 0; m < 4; ++m) {
      int dk0 = wm * 64 + m * 16 + lhi * 4;
      u16x4 o = { f2bf(Mreg[m][0]), f2bf(Mreg[m][1]),
                  f2bf(Mreg[m][2]), f2bf(Mreg[m][3]) };
      *(u16x4*)&MbT[(((size_t)(c * 16 + h)) * 128 + dv0 + dvl) * 128 + dk0] = o;
    }
    __syncthreads();   // prev chunk's LDS reads complete before restage

    // stage k: vectorized f32x4 loads, dual LDS layouts from registers
    {
      int t = tid >> 2, c0 = (tid & 3) * 32;
      const float* kr = kn + ((size_t)h * L_SEQ + l0 + t) * 128 + c0;
#pragma unroll
      for (int j4 = 0; j4 < 8; ++j4) {
        f32x4 v = *(const f32x4*)&kr[j4 * 4];
        u16x4 o = { f2bf(v[0]), f2bf(v[1]), f2bf(v[2]), f2bf(v[3]) };
        *(u16x4*)&kb[t][c0 + j4 * 4] = o;
        kbT[c0 + j4 * 4 + 0][t] = o[0];
        kbT[c0 + j4 * 4 + 1][t] = o[1];
        kbT[c0 + j4 * 4 + 2][t] = o[2];
        kbT[c0 + j4 * 4 + 3][t] = o[3];
      }
    }
    // stage W: Wg16[base + s*64 + t] contiguous in t, already bf16
    {
      size_t base = (size_t)(c * 16 + h) * 4096;
#pragma unroll
      for (int i = 0; i < 4; ++i) {
        int flat = tid + i * 256;           // 0..1023
        int s = flat >> 4, t0 = (flat & 15) * 4;
        u16x4 v = *(const u16x4*)&Wg16[base + (size_t)s * 64 + t0];
        Wbf[t0 + 0][s] = v[0];
        Wbf[t0 + 1][s] = v[1];
        Wbf[t0 + 2][s] = v[2];
        Wbf[t0 + 3][s] = v[3];
      }
    }
    if (tid < 64) {
      gsh[tid] = gT[h * L_SEQ + l0 + tid];
      bts[tid] = btT[h * L_SEQ + l0 + tid];
    }
    __syncthreads();
    if (tid < 64) {
      float a = 0.f;
      for (int u = 0; u <= tid; ++u) a += gsh[u];
      Gh[tid] = a;
    }
    __syncthreads();

    // ---- KM = K @ M_in (64x32, K=128); r = beta(v - e^Gh*KM) -> rTb ----
    {
      f32x4 acc[2] = {};
#pragma unroll
      for (int kk = 0; kk < 128; kk += 32) {
        const int koff = kk + lhi * 8;
        bf16x8 b0 = *(const bf16x8*)&MbfT[dvl][koff];
#pragma unroll
        for (int m = 0; m < 2; ++m) {
          bf16x8 a = *(const bf16x8*)&kb[wm * 32 + m * 16 + l15][koff];
          acc[m] = __builtin_amdgcn_mfma_f32_16x16x32_bf16(a, b0, acc[m], 0, 0, 0);
        }
      }
#pragma unroll
      for (int m = 0; m < 2; ++m) {
        int t0 = wm * 32 + m * 16 + lhi * 4;
        f32x4 v4 = *(const f32x4*)&vT[(size_t)(h * 128 + dv0 + dvl) * L_SEQ + l0 + t0];
#pragma unroll
        for (int j = 0; j < 4; ++j) {
          int t = t0 + j;
          float r = bts[t] * (v4[j] - expf(Gh[t]) * acc[m][j]);
          rTb[dvl][t] = f2bf(r);
        }
      }
    }
    __syncthreads();

    // ---- delta = W @ r (64x32, K=64) -> DbT16 bf16; decayed -> ddT bf16 ----
    {
      f32x4 acc[2] = {};
#pragma unroll
      for (int kk = 0; kk < 64; kk += 32) {
        const int koff = kk + lhi * 8;
        bf16x8 b0 = *(const bf16x8*)&rTb[dvl][koff];
#pragma unroll
        for (int m = 0; m < 2; ++m) {
          bf16x8 a = *(const bf16x8*)&Wbf[wm * 32 + m * 16 + l15][koff];
          acc[m] = __builtin_amdgcn_mfma_f32_16x16x32_bf16(a, b0, acc[m], 0, 0, 0);
        }
      }
      const float G63 = Gh[63];
#pragma unroll
      for (int m = 0; m < 2; ++m) {
        int t0 = wm * 32 + m * 16 + lhi * 4;
        u16x4 od = { f2bf(acc[m][0]), f2bf(acc[m][1]),
                     f2bf(acc[m][2]), f2bf(acc[m][3]) };
        *(u16x4*)&DbT16[(size_t)(h * 128 + dv0 + dvl) * L_SEQ + l0 + t0] = od;
#pragma unroll
        for (int j = 0; j < 4; ++j) {
          int t = t0 + j;
          ddT[dvl][t] = f2bf(acc[m][j] * expf(G63 - Gh[t]));
        }
      }
    }
    __syncthreads();

    // ---- M = E63*M + K^T @ ddT (128x32, K=64); refresh bf16 mirror ----
    {
      const float E63 = expf(Gh[63]);
      f32x4 acc[4];
#pragma unroll
      for (int m = 0; m < 4; ++m)
#pragma unroll
        for (int j = 0; j < 4; ++j) acc[m][j] = E63 * Mreg[m][j];
#pragma unroll
      for (int kk = 0; kk < 64; kk += 32) {
        const int koff = kk + lhi * 8;
        bf16x8 b0 = *(const bf16x8*)&ddT[dvl][koff];
#pragma unroll
        for (int m = 0; m < 4; ++m) {
          bf16x8 a = *(const bf16x8*)&kbT[wm * 64 + m * 16 + l15][koff];
          acc[m] = __builtin_amdgcn_mfma_f32_16x16x32_bf16(a, b0, acc[m], 0, 0, 0);
        }
      }
#pragma unroll
      for (int m = 0; m < 4; ++m) {
        Mreg[m] = acc[m];
        int dk0 = wm * 64 + m * 16 + lhi * 4;
#pragma unroll
        for (int j = 0; j < 4; ++j)
          MbfT[dvl][dk0 + j] = f2bf(acc[m][j]);
      }
    }
    __syncthreads();
  }
}

// ---------------- MFMA output reconstruction + fused gated RMSNorm ----------
// bf16 MbT/DbT16 loads (bitwise-identical operands to R22's convert-on-read).
__global__ __launch_bounds__(256) void opass_kernel(const float* __restrict__ qn,
                                                    const float* __restrict__ kn,
                                                    const u16* __restrict__ DbT16,
                                                    const float* __restrict__ gT,
                                                    const u16* __restrict__ MbT,
                                                    const float* __restrict__ qkvz,
                                                    const float* __restrict__ norm_w,
                                                    u16* __restrict__ gn) {
  __shared__ alignas(16) u16 qsb[64][136];
  __shared__ alignas(16) u16 bbuf[128][136];
  __shared__ alignas(16) u16 Asb[64][72];
  __shared__ float gsh[64], Gh[64];
  __shared__ float ssr[2][64];

  const int tid = threadIdx.x;
  const int lane = tid & 63, wave = tid >> 6;
  const int l15 = lane & 15, lhi = lane >> 4;
  const int h = blockIdx.x & 15, sc = blockIdx.x >> 4;
  const int l0 = sc * SCH;

  {
    int t = tid >> 2, c0 = (tid & 3) * 32;
    const float* qr = qn + ((size_t)h * L_SEQ + l0 + t) * 128 + c0;
    const float* kr = kn + ((size_t)h * L_SEQ + l0 + t) * 128 + c0;
#pragma unroll
    for (int j = 0; j < 8; ++j) {
      f32x4 vq = *(const f32x4*)&qr[j * 4];
      f32x4 vk = *(const f32x4*)&kr[j * 4];
      u16x4 oq = { f2bf(vq[0]), f2bf(vq[1]), f2bf(vq[2]), f2bf(vq[3]) };
      u16x4 ok = { f2bf(vk[0]), f2bf(vk[1]), f2bf(vk[2]), f2bf(vk[3]) };
      *(u16x4*)&qsb[t][c0 + j * 4] = oq;
      *(u16x4*)&bbuf[t][c0 + j * 4] = ok;
    }
  }
  if (tid < 64) gsh[tid] = gT[h * L_SEQ + l0 + tid];
  __syncthreads();
  if (tid < 64) {
    float a = 0.f;
    for (int u = 0; u <= tid; ++u) a += gsh[u];
    Gh[tid] = a;
  }
  __syncthreads();

  f32x4 acc1[2][2] = {};
  const int wm = wave >> 1, wn = wave & 1;
#pragma unroll
  for (int kk = 0; kk < 128; kk += 32) {
    const int koff = kk + lhi * 8;
    bf16x8 a[2], b[2];
#pragma unroll
    for (int m = 0; m < 2; ++m)
      a[m] = *(const bf16x8*)&qsb[wm * 32 + m * 16 + l15][koff];
#pragma unroll
    for (int n = 0; n < 2; ++n)
      b[n] = *(const bf16x8*)&bbuf[wn * 32 + n * 16 + l15][koff];
#pragma unroll
    for (int m = 0; m < 2; ++m)
#pragma unroll
      for (int n = 0; n < 2; ++n)
        acc1[m][n] = __builtin_amdgcn_mfma_f32_16x16x32_bf16(a[m], b[n], acc1[m][n], 0, 0, 0);
  }
#pragma unroll
  for (int m = 0; m < 2; ++m)
#pragma unroll
    for (int n = 0; n < 2; ++n)
#pragma unroll
      for (int j = 0; j < 4; ++j) {
        int t = wm * 32 + m * 16 + lhi * 4 + j;
        int s = wn * 32 + n * 16 + l15;
        float a = (s <= t) ? acc1[m][n][j] * expf(Gh[t] - Gh[s]) : 0.f;
        Asb[t][s] = f2bf(a);
      }
  __syncthreads();

  {  // M_in: straight bf16 copy (no conversion)
    int dv = tid >> 1, c0 = (tid & 1) * 64;
    const u16* mr = MbT + (((size_t)sc * 16 + h) * 128 + dv) * 128 + c0;
#pragma unroll
    for (int j = 0; j < 8; ++j)
      *(bf16x8*)&bbuf[dv][c0 + j * 8] = *(const bf16x8*)&mr[j * 8];
  }
  __syncthreads();

  f32x4 acc[2][4] = {};
#pragma unroll
  for (int kk = 0; kk < 128; kk += 32) {
    const int koff = kk + lhi * 8;
    bf16x8 a[2], b[4];
#pragma unroll
    for (int m = 0; m < 2; ++m)
      a[m] = *(const bf16x8*)&qsb[wm * 32 + m * 16 + l15][koff];
#pragma unroll
    for (int n = 0; n < 4; ++n)
      b[n] = *(const bf16x8*)&bbuf[wn * 64 + n * 16 + l15][koff];
#pragma unroll
    for (int m = 0; m < 2; ++m)
#pragma unroll
      for (int n = 0; n < 4; ++n)
        acc[m][n] = __builtin_amdgcn_mfma_f32_16x16x32_bf16(a[m], b[n], acc[m][n], 0, 0, 0);
  }
#pragma unroll
  for (int m = 0; m < 2; ++m) {
#pragma unroll
    for (int j = 0; j < 4; ++j) {
      int t = wm * 32 + m * 16 + lhi * 4 + j;
      float sc1 = expf(Gh[t]);
#pragma unroll
      for (int n = 0; n < 4; ++n) acc[m][n][j] *= sc1;
    }
  }
  __syncthreads();

  {  // D^T: straight bf16 copy (no conversion)
    int dv = tid >> 1, c0 = (tid & 1) * 32;
    const u16* dr = DbT16 + (size_t)(h * 128 + dv) * L_SEQ + l0 + c0;
#pragma unroll
    for (int j = 0; j < 4; ++j)
      *(bf16x8*)&bbuf[dv][c0 + j * 8] = *(const bf16x8*)&dr[j * 8];
  }
  __syncthreads();

#pragma unroll
  for (int kk = 0; kk < 64; kk += 32) {
    const int koff = kk + lhi * 8;
    bf16x8 a[2], b[4];
#pragma unroll
    for (int m = 0; m < 2; ++m)
      a[m] = *(const bf16x8*)&Asb[wm * 32 + m * 16 + l15][koff];
#pragma unroll
    for (int n = 0; n < 4; ++n)
      b[n] = *(const bf16x8*)&bbuf[wn * 64 + n * 16 + l15][koff];
#pragma unroll
    for (int m = 0; m < 2; ++m)
#pragma unroll
      for (int n = 0; n < 4; ++n)
        acc[m][n] = __builtin_amdgcn_mfma_f32_16x16x32_bf16(a[m], b[n], acc[m][n], 0, 0, 0);
  }

  float pr[2][4];
#pragma unroll
  for (int m = 0; m < 2; ++m)
#pragma unroll
    for (int j = 0; j < 4; ++j) {
      float p = 0.f;
#pragma unroll
      for (int n = 0; n < 4; ++n) p = fmaf(acc[m][n][j], acc[m][n][j], p);
      pr[m][j] = red16(p);
    }
  if (l15 == 0) {
#pragma unroll
    for (int m = 0; m < 2; ++m)
#pragma unroll
      for (int j = 0; j < 4; ++j)
        ssr[wn][wm * 32 + m * 16 + lhi * 4 + j] = pr[m][j];
  }
  __syncthreads();
#pragma unroll
  for (int m = 0; m < 2; ++m)
#pragma unroll
    for (int j = 0; j < 4; ++j) {
      int t = wm * 32 + m * 16 + lhi * 4 + j;
      float ss = ssr[0][t] + ssr[1][t];
      float r = 1.f / sqrtf(ss * (1.f / 128.f) + 1e-6f);
      const float* zp = qkvz + (size_t)(l0 + t) * QZD + CONVD + h * 128;
      u16* dst = gn + (size_t)(l0 + t) * VALD + h * 128;
#pragma unroll
      for (int n = 0; n < 4; ++n) {
        int dv = wn * 64 + n * 16 + l15;
        float z = zp[dv];
        float sil = z / (1.f + expf(-z));
        dst[dv] = f2bf(acc[m][n][j] * r * norm_w[dv] * sil);
      }
    }
}

extern "C" void kernel_launch(void* const* d_in, const int* in_sizes, int n_in,
                              void* d_out, int out_size, void* d_ws, size_t ws_size,
                              hipStream_t stream) {
  const float* x      = (const float*)d_in[0];
  const float* Wqkv   = (const float*)d_in[1];
  const float* Wz     = (const float*)d_in[2];
  const float* Wb     = (const float*)d_in[3];
  const float* Wa     = (const float*)d_in[4];
  const float* conv_w = (const float*)d_in[5];
  const float* A_log  = (const float*)d_in[6];
  const float* dt_bias= (const float*)d_in[7];
  const float* norm_w = (const float*)d_in[8];
  const float* Wout   = (const float*)d_in[9];
  float* out = (float*)d_out;

  char* ws = (char*)d_ws;
  size_t off = 0;
  auto alloc = [&](size_t bytes) {
    void* p = ws + off;
    off = (off + bytes + 255) & ~(size_t)255;
    return p;
  };
  u16* xb     = (u16*)alloc((size_t)L_SEQ * IDIM_ * 2);
  u16* WcatT  = (u16*)alloc((size_t)QZD * IDIM_ * 2);
  u16* WoutT  = (u16*)alloc((size_t)IDIM_ * VALD * 2);
  float* qkvz = (float*)alloc((size_t)L_SEQ * QZD * 4);
  float* qn   = (float*)alloc((size_t)H_ * L_SEQ * 128 * 4);
  float* kn   = (float*)alloc((size_t)H_ * L_SEQ * 128 * 4);
  float* vT   = (float*)alloc((size_t)H_ * 128 * L_SEQ * 4);
  float* btT  = (float*)alloc((size_t)L_SEQ * H_ * 4);
  float* gTb  = (float*)alloc((size_t)L_SEQ * H_ * 4);
  u16* Wg16   = (u16*)alloc((size_t)NSC * H_ * 64 * 64 * 2);     // 2MB
  u16* MbT    = (u16*)alloc((size_t)NSC * H_ * 128 * 128 * 2);   // 8MB
  u16* DbT16  = (u16*)alloc((size_t)H_ * 128 * L_SEQ * 2);       // 4MB
  u16* gn     = (u16*)alloc((size_t)L_SEQ * VALD * 2);

  // merged casts/transposes + gate-weight rows + zero pad (1 launch)
  prepcast_kernel<<<22616, 256, 0, stream>>>(x, Wqkv, Wz, Wb, Wa, Wout, xb, WcatT, WoutT);

  // combined projection [qkv | z | gates]
  gemm_bt_kernel<<<dim3(QZD / 128, L_SEQ / 128), 256, 0, stream>>>(xb, WcatT, qkvz, L_SEQ, QZD, IDIM_);

  // gates
  gatelite_kernel<<<64, 256, 0, stream>>>(qkvz, A_log, dt_bias, btT, gTb);

  // merged prep2
  prep2_kernel<<<6144, 256, 0, stream>>>(qkvz, conv_w, qn, kn, vT);

  // chunked-WY scan: W precompute (parallel) + MFMA chunk recurrence (64 blocks)
  winv_kernel<<<NSC * H_, 256, 0, stream>>>(kn, gTb, btT, Wg16);
  wyscan_kernel<<<H_ * 4, 256, 0, stream>>>(kn, vT, gTb, btT, Wg16, MbT, DbT16);

  // MFMA output reconstruction + fused gated RMSNorm
  opass_kernel<<<NSC * H_, 256, 0, stream>>>(qn, kn, DbT16, gTb, MbT, qkvz, norm_w, gn);

  // final projection
  gemm_bt64_kernel<<<256, 256, 0, stream>>>(gn, WoutT, out, L_SEQ, IDIM_, VALD, 1);
}